// Round 2
// baseline (402.302 us; speedup 1.0000x reference)
//
#include <hip/hip_runtime.h>
#include <stdint.h>
#include <stddef.h>

#define NEG 0.1f

typedef __attribute__((ext_vector_type(8))) short short8;
typedef __attribute__((ext_vector_type(16))) float floatx16;

__device__ __forceinline__ unsigned f2bf(float f) {
  union { float f; unsigned u; } v; v.f = f;
  unsigned r = v.u + 0x7FFFu + ((v.u >> 16) & 1u);   // RNE
  return r >> 16;
}
__device__ __forceinline__ float bits2f(unsigned u) {
  union { unsigned u; float f; } v; v.u = u; return v.f;
}
__device__ __forceinline__ float lrelu(float x) { return fmaxf(x, NEG * x); }

// ---------------- fused prep: transpose-x | conv-w bf16 | wab | wmlp | hc
__global__ void k_prep(const float* __restrict__ x, float* __restrict__ xt,
                       const float* __restrict__ cw1, const float* __restrict__ cw2,
                       const float* __restrict__ cw3, const float* __restrict__ cw4,
                       unsigned short* __restrict__ wt1, unsigned short* __restrict__ wt2,
                       unsigned short* __restrict__ wt3, unsigned short* __restrict__ wt4,
                       const float* __restrict__ W1, unsigned short* __restrict__ wab,
                       const float* __restrict__ W2, const float* __restrict__ W3,
                       const float* __restrict__ W4, unsigned short* __restrict__ wmlp,
                       const float* __restrict__ h, const float* __restrict__ b1,
                       float* __restrict__ hc) {
  __shared__ float shm[256];
  int bid = blockIdx.x, tid = threadIdx.x;
  if (bid < 1600) {                       // transpose x (L,B,E)->(B,L,E): 2 rows/block
    int r = bid * 2 + (tid >> 7);
    int b = r / 100, l = r - b * 100;
    const float4* src = (const float4*)(x + (size_t)(l * 32 + b) * 512);
    float4* dst = (float4*)(xt + (size_t)r * 512);
    dst[tid & 127] = src[tid & 127];
  } else if (bid < 2880) {                // conv weights: Wt[f][ks*E+e] = cw[f][e][ks]
    int z = bid - 1600;
    int E; const float* cw; unsigned short* wt;
    if (z < 512) { E = 512; cw = cw1; wt = wt1; }
    else {
      int q = (z - 512) >> 8; E = 256;
      cw = (q == 0) ? cw2 : ((q == 1) ? cw3 : cw4);
      wt = (q == 0) ? wt2 : ((q == 1) ? wt3 : wt4);
      z = (z - 512) & 255;
    }
    int idx = z * 256 + tid;              // over F*E
    int f = idx / E, e = idx - f * E;
    const float* s = cw + (size_t)idx * 3;
    unsigned short* d = wt + (size_t)f * 3 * E + e;
    d[0] = (unsigned short)f2bf(s[0]);
    d[E] = (unsigned short)f2bf(s[1]);
    d[2 * E] = (unsigned short)f2bf(s[2]);
  } else if (bid < 3264) {                // wab: [n][kp], kp padded 258->384
    int idx = (bid - 2880) * 256 + tid;   // 256*384
    int n = idx / 384, kp = idx - n * 384;
    float v = 0.f;
    if (kp < 258) { int d = (n < 128) ? kp : (258 + kp); v = W1[(size_t)d * 128 + (n & 127)]; }
    wab[idx] = (unsigned short)f2bf(v);
  } else if (bid < 3456) {                // wmlp: wt[z][n][k] = Wz[k*128+n]
    int i = (bid - 3264) * 256 + tid;     // 0..49151
    int zz = i >> 14, idx = i & 16383;
    const float* W = (zz == 0) ? W2 : ((zz == 1) ? W3 : W4);
    int n = idx >> 7, k = idx & 127;
    wmlp[i] = (unsigned short)f2bf(W[k * 128 + n]);
  } else {                                // hc[b][m] = h[b]@Wc + b1 (2-way k-split)
    int b = bid - 3456;
    int m = tid & 127, kh = tid >> 7;
    const float* hr = h + b * 512;
    float acc = kh ? 0.f : b1[m];
    for (int k = kh * 256; k < kh * 256 + 256; ++k)
      acc += hr[k] * W1[(size_t)(516 + k) * 128 + m];
    shm[tid] = acc;
    __syncthreads();
    if (tid < 128) hc[b * 128 + tid] = shm[tid] + shm[tid + 128];
  }
}

// ---------------- im2col layer1: I[r][ks*512+e] = xt[b][l+ks-1][e] (zero pad), bf16
__global__ void k_im2col1(const float* __restrict__ xt, unsigned short* __restrict__ I) {
  int idx = blockIdx.x * 256 + threadIdx.x;     // r*192 + seg
  int r = idx / 192, seg = idx - r * 192;
  int b = r / 100, l = r - b * 100;
  int k = seg * 8, ks = k >> 9, e = k & 511;
  int lp = l + ks - 1;
  uint4 val;
  if (lp < 0 || lp >= 100) { val.x = val.y = val.z = val.w = 0u; }
  else {
    const float* s = xt + ((size_t)(b * 100 + lp) * 512 + e);
    float4 f0 = *(const float4*)(s);
    float4 f1 = *(const float4*)(s + 4);
    val.x = f2bf(f0.x) | (f2bf(f0.y) << 16);
    val.y = f2bf(f0.z) | (f2bf(f0.w) << 16);
    val.z = f2bf(f1.x) | (f2bf(f1.y) << 16);
    val.w = f2bf(f1.z) | (f2bf(f1.w) << 16);
  }
  *(uint4*)(I + (size_t)idx * 8) = val;
}

// ---------------- im2col + BN-apply (layers 2..4 input)
__global__ void k_im2col_bn(const float* __restrict__ z, const float* __restrict__ bs,
                            const float* __restrict__ gam, const float* __restrict__ bet,
                            unsigned short* __restrict__ I) {
  int idx = blockIdx.x * 256 + threadIdx.x;     // r*96 + seg
  int r = idx / 96, seg = idx - r * 96;
  int b = r / 100, l = r - b * 100;
  int k = seg * 8, ks = k >> 8, e = k & 255;
  int lp = l + ks - 1;
  unsigned o[8];
  if (lp < 0 || lp >= 100) {
    for (int i = 0; i < 8; ++i) o[i] = 0;
  } else {
    const float* s = z + ((size_t)(b * 100 + lp) * 256 + e);
    const float inv = 1.f / 3200.f;
    for (int i = 0; i < 8; ++i) {
      float m = bs[e + i] * inv;
      float var = bs[256 + e + i] * inv - m * m;
      float sc = gam[e + i] * rsqrtf(var + 1e-5f);
      float sh = bet[e + i] - m * sc;
      o[i] = f2bf(s[i] * sc + sh);
    }
  }
  uint4 val;
  val.x = o[0] | (o[1] << 16); val.y = o[2] | (o[3] << 16);
  val.z = o[4] | (o[5] << 16); val.w = o[6] | (o[7] << 16);
  *(uint4*)(I + (size_t)idx * 8) = val;
}

// ---------------- xf build: BN-apply layer4 + coords, K padded 258->384, bf16
__global__ void k_prepxf(const float* __restrict__ z, const float* __restrict__ bs,
                         const float* __restrict__ gam, const float* __restrict__ bet,
                         unsigned short* __restrict__ xfb) {
  int idx = blockIdx.x * 256 + threadIdx.x;    // r*48 + seg
  int r = idx / 48, seg = idx - r * 48;
  int l = r % 100;
  int k = seg * 8;
  unsigned o[8];
  if (k < 256) {
    const float* s = z + ((size_t)r * 256 + k);
    const float inv = 1.f / 3200.f;
    for (int i = 0; i < 8; ++i) {
      float m = bs[k + i] * inv;
      float var = bs[256 + k + i] * inv - m * m;
      float sc = gam[k + i] * rsqrtf(var + 1e-5f);
      float sh = bet[k + i] - m * sc;
      o[i] = f2bf(s[i] * sc + sh);
    }
  } else {
    for (int i = 0; i < 8; ++i) o[i] = 0;
    if (k == 256) {
      o[0] = f2bf(((float)l * 0.1f - 2.0f) * 0.5f);
      o[1] = f2bf(((float)(l % 10) - 2.0f) * 0.5f);
    }
  }
  uint4 val;
  val.x = o[0] | (o[1] << 16); val.y = o[2] | (o[3] << 16);
  val.z = o[4] | (o[5] << 16); val.w = o[6] | (o[7] << 16);
  *(uint4*)(xfb + (size_t)idx * 8) = val;
}

// ---------------- conv GEMM: 64x64 tile, 4 waves of 32x32, K-chunk 128 in LDS
__global__ __launch_bounds__(256) void k_convgemm(
    const unsigned short* __restrict__ G, const unsigned short* __restrict__ Wt, int K,
    const float* __restrict__ cb, float* __restrict__ z, float* __restrict__ bsum) {
  __shared__ unsigned short Gs[64 * 136];
  __shared__ unsigned short Ws[64 * 136];
  int tid = threadIdx.x;
  int lane = tid & 63, wave = tid >> 6;
  int rt = blockIdx.x, ct = blockIdx.y;
  int rh = wave & 1, ch = wave >> 1;
  floatx16 acc;
#pragma unroll
  for (int i = 0; i < 16; ++i) acc[i] = 0.f;
  int row_s = tid >> 4, seg = tid & 15;
  int mrow = lane & 31;
  int koff = (lane >> 5) << 3;
  for (int kc = 0; kc < K; kc += 128) {
#pragma unroll
    for (int it = 0; it < 4; ++it) {
      int rr = row_s + it * 16;
      *(uint4*)(&Gs[rr * 136 + seg * 8]) = *(const uint4*)(G + ((size_t)(rt * 64 + rr) * K + kc + seg * 8));
      *(uint4*)(&Ws[rr * 136 + seg * 8]) = *(const uint4*)(Wt + ((size_t)(ct * 64 + rr) * K + kc + seg * 8));
    }
    __syncthreads();
#pragma unroll
    for (int kk = 0; kk < 8; ++kk) {
      short8 a = *(const short8*)(&Gs[(rh * 32 + mrow) * 136 + kk * 16 + koff]);
      short8 w8 = *(const short8*)(&Ws[(ch * 32 + mrow) * 136 + kk * 16 + koff]);
      acc = __builtin_amdgcn_mfma_f32_32x32x16_bf16(a, w8, acc, 0, 0, 0);
    }
    __syncthreads();
  }
  int f = ct * 64 + ch * 32 + mrow;
  float bias = cb[f];
  float s1 = 0.f, s2 = 0.f;
#pragma unroll
  for (int reg = 0; reg < 16; ++reg) {
    int rowp = (reg & 3) + 8 * (reg >> 2) + 4 * (lane >> 5);
    int row = rt * 64 + rh * 32 + rowp;
    float v = acc[reg] + bias;
    v = fmaxf(v, NEG * v);
    z[(size_t)row * 256 + f] = v;
    s1 += v; s2 += v * v;
  }
  s1 += __shfl_xor(s1, 32, 64);
  s2 += __shfl_xor(s2, 32, 64);
  if (lane < 32) { atomicAdd(&bsum[f], s1); atomicAdd(&bsum[256 + f], s2); }
}

// ---------------- A/C GEMM: [A|C] = xfb(3200x384) @ Wab^T; C gets +hc[b]; bf16 out
__global__ __launch_bounds__(256) void k_acgemm(
    const unsigned short* __restrict__ G, const unsigned short* __restrict__ Wt, int K,
    const float* __restrict__ hc, unsigned short* __restrict__ Abf,
    unsigned short* __restrict__ Cbf) {
  __shared__ unsigned short Gs[64 * 136];
  __shared__ unsigned short Ws[64 * 136];
  int tid = threadIdx.x;
  int lane = tid & 63, wave = tid >> 6;
  int rt = blockIdx.x, ct = blockIdx.y;
  int rh = wave & 1, ch = wave >> 1;
  floatx16 acc;
#pragma unroll
  for (int i = 0; i < 16; ++i) acc[i] = 0.f;
  int row_s = tid >> 4, seg = tid & 15;
  int mrow = lane & 31;
  int koff = (lane >> 5) << 3;
  for (int kc = 0; kc < K; kc += 128) {
#pragma unroll
    for (int it = 0; it < 4; ++it) {
      int rr = row_s + it * 16;
      *(uint4*)(&Gs[rr * 136 + seg * 8]) = *(const uint4*)(G + ((size_t)(rt * 64 + rr) * K + kc + seg * 8));
      *(uint4*)(&Ws[rr * 136 + seg * 8]) = *(const uint4*)(Wt + ((size_t)(ct * 64 + rr) * K + kc + seg * 8));
    }
    __syncthreads();
#pragma unroll
    for (int kk = 0; kk < 8; ++kk) {
      short8 a = *(const short8*)(&Gs[(rh * 32 + mrow) * 136 + kk * 16 + koff]);
      short8 w8 = *(const short8*)(&Ws[(ch * 32 + mrow) * 136 + kk * 16 + koff]);
      acc = __builtin_amdgcn_mfma_f32_32x32x16_bf16(a, w8, acc, 0, 0, 0);
    }
    __syncthreads();
  }
  int n = ct * 64 + ch * 32 + mrow;
#pragma unroll
  for (int reg = 0; reg < 16; ++reg) {
    int rowp = (reg & 3) + 8 * (reg >> 2) + 4 * (lane >> 5);
    int row = rt * 64 + rh * 32 + rowp;
    float v = acc[reg];
    if (n < 128) Abf[(size_t)row * 128 + n] = (unsigned short)f2bf(v);
    else {
      int b = row / 100;
      Cbf[(size_t)row * 128 + (n - 128)] =
          (unsigned short)f2bf(v + hc[b * 128 + (n - 128)]);
    }
  }
}

// ---------------- fused relation MLP: weights from global (L2), gs wave-private in LDS
// block = 128 pair-rows x 128 feat, 4 waves x 32 rows; NO inter-layer barriers
__global__ __launch_bounds__(256, 4) void k_mlp(
    const unsigned short* __restrict__ Abf, const unsigned short* __restrict__ Cbf,
    const unsigned short* __restrict__ Wt, const float* __restrict__ b2,
    const float* __restrict__ b3, const float* __restrict__ b4, float* __restrict__ sout) {
  __shared__ unsigned short gs[128 * 136];   // wave-private 32-row slabs, stride 136 (16B-aligned)
  __shared__ float sblk[128];
  int tid = threadIdx.x;
  int lane = tid & 63, wave = tid >> 6;
  int b = blockIdx.y, tile = blockIdx.x;
  int wb = wave * 32;
  if (tid < 128) sblk[tid] = 0.f;

  {  // g0 = lrelu(C_i + A_j): 2 lanes per row, 64 cols each, bf16 in/out
    int lr = wb + (lane >> 1);
    int hh = lane & 1;
    int r = tile * 128 + lr;
    if (r > 9999) r = 9999;                  // clamp; masked at final sum
    const unsigned short* Crow = Cbf + (size_t)(b * 100 + r / 100) * 128;
    const unsigned short* Arow = Abf + (size_t)(b * 100 + r % 100) * 128;
#pragma unroll
    for (int it = 0; it < 8; ++it) {
      int col = hh * 64 + it * 8;
      uint4 c4 = *(const uint4*)(Crow + col);
      uint4 a4 = *(const uint4*)(Arow + col);
      unsigned ow[4];
      unsigned cw[4] = {c4.x, c4.y, c4.z, c4.w};
      unsigned aw[4] = {a4.x, a4.y, a4.z, a4.w};
#pragma unroll
      for (int q = 0; q < 4; ++q) {
        float c0 = bits2f(cw[q] << 16), c1 = bits2f(cw[q] & 0xFFFF0000u);
        float a0 = bits2f(aw[q] << 16), a1 = bits2f(aw[q] & 0xFFFF0000u);
        float v0 = c0 + a0; v0 = fmaxf(v0, NEG * v0);
        float v1 = c1 + a1; v1 = fmaxf(v1, NEG * v1);
        ow[q] = f2bf(v0) | (f2bf(v1) << 16);
      }
      uint4 o4; o4.x = ow[0]; o4.y = ow[1]; o4.z = ow[2]; o4.w = ow[3];
      *(uint4*)(&gs[lr * 136 + col]) = o4;
    }
  }
  __syncthreads();   // only for sblk init ordering (gs is wave-private)

  int mrow = wb + (lane & 31);
  int koff = (lane >> 5) << 3;
  for (int layer = 0; layer < 3; ++layer) {
    const unsigned short* W = Wt + layer * 16384;
    const float* bia = (layer == 0) ? b2 : ((layer == 1) ? b3 : b4);
    floatx16 acc[4];
#pragma unroll
    for (int nt = 0; nt < 4; ++nt)
#pragma unroll
      for (int i = 0; i < 16; ++i) acc[nt][i] = 0.f;
#pragma unroll
    for (int kk = 0; kk < 8; ++kk) {
      short8 a = *(const short8*)(&gs[mrow * 136 + kk * 16 + koff]);
#pragma unroll
      for (int nt = 0; nt < 4; ++nt) {
        short8 w8 = *(const short8*)(&W[(size_t)(nt * 32 + (lane & 31)) * 128 + kk * 16 + koff]);
        acc[nt] = __builtin_amdgcn_mfma_f32_32x32x16_bf16(a, w8, acc[nt], 0, 0, 0);
      }
    }
    if (layer < 2) {
#pragma unroll
      for (int nt = 0; nt < 4; ++nt) {
        int col = nt * 32 + (lane & 31);
        float bv = bia[col];
#pragma unroll
        for (int reg = 0; reg < 16; ++reg) {
          int rowp = (reg & 3) + 8 * (reg >> 2) + 4 * (lane >> 5);
          float v = acc[nt][reg] + bv;
          v = fmaxf(v, NEG * v);
          gs[(wb + rowp) * 136 + col] = (unsigned short)f2bf(v);
        }
      }
    } else {
#pragma unroll
      for (int nt = 0; nt < 4; ++nt) {
        int col = nt * 32 + (lane & 31);
        float bv = bia[col];
        float cs = 0.f;
#pragma unroll
        for (int reg = 0; reg < 16; ++reg) {
          int rowp = (reg & 3) + 8 * (reg >> 2) + 4 * (lane >> 5);
          int r = tile * 128 + wb + rowp;
          float v = acc[nt][reg] + bv;
          v = fmaxf(v, NEG * v);
          cs += (r < 10000) ? v : 0.f;
        }
        cs += __shfl_xor(cs, 32, 64);
        if (lane < 32) atomicAdd(&sblk[col], cs);
      }
    }
  }
  __syncthreads();
  if (tid < 128) atomicAdd(&sout[(b << 7) + tid], sblk[tid]);
}

// ---------------- final: out = lrelu(lrelu(s@F1+fb1)@F2+fb2), one block per b
__global__ void k_final(const float* __restrict__ s, const float* __restrict__ F1,
                        const float* __restrict__ fb1, const float* __restrict__ F2,
                        const float* __restrict__ fb2, float* __restrict__ out) {
  __shared__ float sl[128], t1[128];
  int b = blockIdx.x, t = threadIdx.x;
  if (t < 128) sl[t] = s[b * 128 + t];
  __syncthreads();
  if (t < 128) {
    float a = fb1[t];
    for (int k = 0; k < 128; ++k) a += sl[k] * F1[k * 128 + t];
    t1[t] = fmaxf(a, NEG * a);
  }
  __syncthreads();
  for (int o = t; o < 512; o += 256) {
    float a = fb2[o];
    for (int k = 0; k < 128; ++k) a += t1[k] * F2[k * 512 + o];
    out[b * 512 + o] = fmaxf(a, NEG * a);
  }
}

extern "C" void kernel_launch(void* const* d_in, const int* in_sizes, int n_in,
                              void* d_out, int out_size, void* d_ws, size_t ws_size,
                              hipStream_t stream) {
  const float* x   = (const float*)d_in[0];
  const float* h   = (const float*)d_in[1];
  const float* cw1 = (const float*)d_in[2];
  const float* cb1 = (const float*)d_in[3];
  const float* g1  = (const float*)d_in[4];
  const float* be1 = (const float*)d_in[5];
  const float* cw2 = (const float*)d_in[6];
  const float* cb2 = (const float*)d_in[7];
  const float* g2  = (const float*)d_in[8];
  const float* be2 = (const float*)d_in[9];
  const float* cw3 = (const float*)d_in[10];
  const float* cb3 = (const float*)d_in[11];
  const float* g3  = (const float*)d_in[12];
  const float* be3 = (const float*)d_in[13];
  const float* cw4 = (const float*)d_in[14];
  const float* cb4 = (const float*)d_in[15];
  const float* g4  = (const float*)d_in[16];
  const float* be4 = (const float*)d_in[17];
  const float* W1  = (const float*)d_in[18];
  const float* b1  = (const float*)d_in[19];
  const float* W2  = (const float*)d_in[20];
  const float* b2  = (const float*)d_in[21];
  const float* W3  = (const float*)d_in[22];
  const float* b3  = (const float*)d_in[23];
  const float* W4  = (const float*)d_in[24];
  const float* b4  = (const float*)d_in[25];
  const float* F1  = (const float*)d_in[26];
  const float* fb1 = (const float*)d_in[27];
  const float* F2  = (const float*)d_in[28];
  const float* fb2 = (const float*)d_in[29];

  char* ws = (char*)d_ws;
  float* bn0  = (float*)(ws + 0);
  float* bn1  = (float*)(ws + 2048);
  float* bn2  = (float*)(ws + 4096);
  float* bn3  = (float*)(ws + 6144);
  float* sbuf = (float*)(ws + 8192);
  float* xt   = (float*)(ws + 24576);
  float* za   = (float*)(ws + 6578176);
  float* zb   = (float*)(ws + 9854976);
  unsigned short* I    = (unsigned short*)(ws + 13131776);
  unsigned short* wt1  = (unsigned short*)(ws + 22962176);
  unsigned short* wt2  = (unsigned short*)(ws + 23748608);
  unsigned short* wt3  = (unsigned short*)(ws + 24141824);
  unsigned short* wt4  = (unsigned short*)(ws + 24535040);
  unsigned short* wab  = (unsigned short*)(ws + 24928256);  // 256x384x2 = 196608
  unsigned short* wmlp = (unsigned short*)(ws + 25124864);  // 98304
  unsigned short* xfb  = (unsigned short*)(ws + 25223168);  // 3200x384x2 = 2457600
  unsigned short* Abf  = (unsigned short*)(ws + 27680768);  // 3200x128x2 = 819200
  unsigned short* Cbf  = (unsigned short*)(ws + 28499968);  // 819200
  float* hc   = (float*)(ws + 29319168);                    // 16384 -> end 29335552
  // total ws use: ~28.0 MB (fits prior-validated 30.5 MB footprint)

  hipMemsetAsync(d_ws, 0, 24576, stream);     // bn sums + s accumulator

  k_prep<<<3488, 256, 0, stream>>>(x, xt, cw1, cw2, cw3, cw4, wt1, wt2, wt3, wt4,
                                   W1, wab, W2, W3, W4, wmlp, h, b1, hc);

  k_im2col1<<<2400, 256, 0, stream>>>(xt, I);
  k_convgemm<<<dim3(50, 4), 256, 0, stream>>>(I, wt1, 1536, cb1, za, bn0);
  k_im2col_bn<<<1200, 256, 0, stream>>>(za, bn0, g1, be1, I);
  k_convgemm<<<dim3(50, 4), 256, 0, stream>>>(I, wt2, 768, cb2, zb, bn1);
  k_im2col_bn<<<1200, 256, 0, stream>>>(zb, bn1, g2, be2, I);
  k_convgemm<<<dim3(50, 4), 256, 0, stream>>>(I, wt3, 768, cb3, za, bn2);
  k_im2col_bn<<<1200, 256, 0, stream>>>(za, bn2, g3, be3, I);
  k_convgemm<<<dim3(50, 4), 256, 0, stream>>>(I, wt4, 768, cb4, zb, bn3);
  k_prepxf<<<600, 256, 0, stream>>>(zb, bn3, g4, be4, xfb);
  k_acgemm<<<dim3(50, 4), 256, 0, stream>>>(xfb, wab, 384, hc, Abf, Cbf);

  k_mlp<<<dim3(79, 32), 256, 0, stream>>>(Abf, Cbf, wmlp, b2, b3, b4, sbuf);
  k_final<<<32, 256, 0, stream>>>(sbuf, F1, fb1, F2, fb2, (float*)d_out);
}

// Round 3
// 363.174 us; speedup vs baseline: 1.1077x; 1.1077x over previous
//
#include <hip/hip_runtime.h>
#include <stdint.h>
#include <stddef.h>

#define NEG 0.1f

typedef __attribute__((ext_vector_type(8))) short short8;
typedef __attribute__((ext_vector_type(16))) float floatx16;

__device__ __forceinline__ unsigned f2bf(float f) {
  union { float f; unsigned u; } v; v.f = f;
  unsigned r = v.u + 0x7FFFu + ((v.u >> 16) & 1u);   // RNE
  return r >> 16;
}
__device__ __forceinline__ float bits2f(unsigned u) {
  union { unsigned u; float f; } v; v.u = u; return v.f;
}
__device__ __forceinline__ float lrelu(float x) { return fmaxf(x, NEG * x); }

// ---------------- fused prep: conv-w bf16 | wab | wmlp(frag order) | hc
__global__ void k_prep(const float* __restrict__ cw1, const float* __restrict__ cw2,
                       const float* __restrict__ cw3, const float* __restrict__ cw4,
                       unsigned short* __restrict__ wt1, unsigned short* __restrict__ wt2,
                       unsigned short* __restrict__ wt3, unsigned short* __restrict__ wt4,
                       const float* __restrict__ W1, unsigned short* __restrict__ wab,
                       const float* __restrict__ W2, const float* __restrict__ W3,
                       const float* __restrict__ W4, unsigned short* __restrict__ wmlp,
                       const float* __restrict__ h, const float* __restrict__ b1,
                       float* __restrict__ hc) {
  __shared__ float shm[256];
  int bid = blockIdx.x, tid = threadIdx.x;
  if (bid < 1280) {                       // conv weights: Wt[f][ks*E+e] = cw[f][e][ks]
    int z = bid;
    int E; const float* cw; unsigned short* wt;
    if (z < 512) { E = 512; cw = cw1; wt = wt1; }
    else {
      int q = (z - 512) >> 8; E = 256;
      cw = (q == 0) ? cw2 : ((q == 1) ? cw3 : cw4);
      wt = (q == 0) ? wt2 : ((q == 1) ? wt3 : wt4);
      z = (z - 512) & 255;
    }
    int idx = z * 256 + tid;              // over F*E
    int f = idx / E, e = idx - f * E;
    const float* s = cw + (size_t)idx * 3;
    unsigned short* d = wt + (size_t)f * 3 * E + e;
    d[0] = (unsigned short)f2bf(s[0]);
    d[E] = (unsigned short)f2bf(s[1]);
    d[2 * E] = (unsigned short)f2bf(s[2]);
  } else if (bid < 1664) {                // wab: [n][kp], kp padded 258->384
    int idx = (bid - 1280) * 256 + tid;   // 256*384
    int n = idx / 384, kp = idx - n * 384;
    float v = 0.f;
    if (kp < 258) { int d = (n < 128) ? kp : (258 + kp); v = W1[(size_t)d * 128 + (n & 127)]; }
    wab[idx] = (unsigned short)f2bf(v);
  } else if (bid < 1856) {                // wmlp in MFMA-B-fragment order:
    // out[((z*4+w)*8+kk)*512 + l*8 + j] = Wz[k*128+n], n=w*32+(l&31), k=kk*16+(l>>5)*8+j
    int i = (bid - 1664) * 256 + tid;     // 0..49151
    int j = i & 7, l = (i >> 3) & 63, kk = (i >> 9) & 7, w = (i >> 12) & 3, zz = i >> 14;
    const float* W = (zz == 0) ? W2 : ((zz == 1) ? W3 : W4);
    int n = w * 32 + (l & 31);
    int k = kk * 16 + ((l >> 5) << 3) + j;
    wmlp[i] = (unsigned short)f2bf(W[k * 128 + n]);
  } else {                                // hc[b][m] = h[b]@Wc + b1 (2-way k-split)
    int b = bid - 1856;
    int m = tid & 127, kh = tid >> 7;
    const float* hr = h + b * 512;
    float acc = kh ? 0.f : b1[m];
    for (int k = kh * 256; k < kh * 256 + 256; ++k)
      acc += hr[k] * W1[(size_t)(516 + k) * 128 + m];
    shm[tid] = acc;
    __syncthreads();
    if (tid < 128) hc[b * 128 + tid] = shm[tid] + shm[tid + 128];
  }
}

// ---------------- conv (implicit im2col + fused input-BN + epilogue BN-sums)
// grid (100,4), 64 threads. Tile: 32 rows x 64 f-cols. K = 3*E, chunks of 64.
__global__ __launch_bounds__(64, 2) void k_conv(
    const float* __restrict__ zin, const float* __restrict__ bnin,
    const float* __restrict__ gamv, const float* __restrict__ betv,
    const unsigned short* __restrict__ wt, const float* __restrict__ cb,
    float* __restrict__ zout, float* __restrict__ bnout, int E, int xmode) {
  extern __shared__ unsigned short smem[];
  const int SL = (E == 512) ? 520 : 264;     // slab stride (shorts), dword-stride % 32 == 4
  unsigned short* slab = smem;               // 34 x SL
  unsigned short* Bs = smem + 34 * SL;       // 64 x 72
  const int K = 3 * E, NC = K >> 6;
  const int esh = (E == 512) ? 9 : 8;
  int lane = threadIdx.x;
  int r0 = blockIdx.x * 32, ct = blockIdx.y;
  int i32 = lane & 31;
  int koff = (lane >> 5) << 3;

  // validity per ks for this lane's tile-row
  int lrow = (r0 + i32) % 100;
  bool vks0 = (lrow >= 1), vks2 = (lrow <= 98);

  // ---- stage input slab (rows m = r0-1 .. r0+32, clamped; garbage rows masked later)
  if (xmode) {  // conv1: read x (L,B,E) layout, no BN, E=512
#pragma unroll 2
    for (int s = 0; s < 34; ++s) {
      int m = r0 - 1 + s; m = min(max(m, 0), 3199);
      int b = m / 100, l = m - b * 100;
      size_t base = (size_t)(l * 32 + b) * 512;
#pragma unroll
      for (int cc = 0; cc < 2; ++cc) {
        int ch = cc * 256 + lane * 4;
        float4 v = *(const float4*)(zin + base + ch);
        uint2 p;
        p.x = f2bf(v.x) | (f2bf(v.y) << 16);
        p.y = f2bf(v.z) | (f2bf(v.w) << 16);
        *(uint2*)(&slab[s * SL + ch]) = p;
      }
    }
  } else {      // convs 2-4: read z (m,256) layout with BN applied
    const float inv = 1.f / 3200.f;
    float sc[4], sh[4];
#pragma unroll
    for (int q = 0; q < 4; ++q) {
      int ch = lane * 4 + q;
      float mme = bnin[ch] * inv;
      float var = bnin[256 + ch] * inv - mme * mme;
      sc[q] = gamv[ch] * rsqrtf(var + 1e-5f);
      sh[q] = betv[ch] - mme * sc[q];
    }
#pragma unroll 4
    for (int s = 0; s < 34; ++s) {
      int m = r0 - 1 + s; m = min(max(m, 0), 3199);
      float4 v = *(const float4*)(zin + (size_t)m * 256 + lane * 4);
      uint2 p;
      p.x = f2bf(v.x * sc[0] + sh[0]) | (f2bf(v.y * sc[1] + sh[1]) << 16);
      p.y = f2bf(v.z * sc[2] + sh[2]) | (f2bf(v.w * sc[3] + sh[3]) << 16);
      *(uint2*)(&slab[s * SL + lane * 4]) = p;
    }
  }

  floatx16 acc0, acc1;
#pragma unroll
  for (int q = 0; q < 16; ++q) { acc0[q] = 0.f; acc1[q] = 0.f; }

  // ---- K loop over 64-wide chunks; B chunk staged in LDS w/ register prefetch
  int brow = lane >> 3, bseg = (lane & 7) * 8;
  uint4 pre[8];
#pragma unroll
  for (int t = 0; t < 8; ++t)
    pre[t] = *(const uint4*)(wt + (size_t)(ct * 64 + t * 8 + brow) * K + bseg);

  for (int c = 0; c < NC; ++c) {
#pragma unroll
    for (int t = 0; t < 8; ++t)
      *(uint4*)(&Bs[(t * 8 + brow) * 72 + bseg]) = pre[t];
    if (c + 1 < NC) {
#pragma unroll
      for (int t = 0; t < 8; ++t)
        pre[t] = *(const uint4*)(wt + (size_t)(ct * 64 + t * 8 + brow) * K + (c + 1) * 64 + bseg);
    }
    int ks = (c << 6) >> esh;
    int ebase = (c << 6) & (E - 1);
    bool v = (ks == 0) ? vks0 : ((ks == 2) ? vks2 : true);
    int srow = i32 + ks;
#pragma unroll
    for (int kk = 0; kk < 4; ++kk) {
      short8 a = {};
      if (v) a = *(const short8*)(&slab[srow * SL + ebase + kk * 16 + koff]);
      short8 b0 = *(const short8*)(&Bs[i32 * 72 + kk * 16 + koff]);
      short8 b1 = *(const short8*)(&Bs[(32 + i32) * 72 + kk * 16 + koff]);
      acc0 = __builtin_amdgcn_mfma_f32_32x32x16_bf16(a, b0, acc0, 0, 0, 0);
      acc1 = __builtin_amdgcn_mfma_f32_32x32x16_bf16(a, b1, acc1, 0, 0, 0);
    }
  }

  // ---- epilogue: bias + lrelu, store z fp32, BN sum/sumsq atomics
#pragma unroll
  for (int nt = 0; nt < 2; ++nt) {
    int f = ct * 64 + nt * 32 + i32;
    float bias = cb[f];
    float s1 = 0.f, s2 = 0.f;
#pragma unroll
    for (int reg = 0; reg < 16; ++reg) {
      int rowp = (reg & 3) + 8 * (reg >> 2) + 4 * (lane >> 5);
      int m = r0 + rowp;
      float v = (nt ? acc1[reg] : acc0[reg]) + bias;
      v = fmaxf(v, NEG * v);
      zout[(size_t)m * 256 + f] = v;
      s1 += v; s2 += v * v;
    }
    s1 += __shfl_xor(s1, 32, 64);
    s2 += __shfl_xor(s2, 32, 64);
    if (lane < 32) { atomicAdd(&bnout[f], s1); atomicAdd(&bnout[256 + f], s2); }
  }
}

// ---------------- A/C GEMM w/ fused BN4 + coords (implicit xf build)
// grid (100,4), 64 threads. Tile 32 rows x 64 n-cols, K padded to 320.
__global__ __launch_bounds__(64, 2) void k_ac(
    const float* __restrict__ zin, const float* __restrict__ bnin,
    const float* __restrict__ gamv, const float* __restrict__ betv,
    const unsigned short* __restrict__ wab, const float* __restrict__ hc,
    unsigned short* __restrict__ Abf, unsigned short* __restrict__ Cbf) {
  __shared__ unsigned short slab[32 * 328];   // stride 328: dword-stride % 32 == 4
  __shared__ unsigned short Bs[64 * 72];
  int lane = threadIdx.x;
  int r0 = blockIdx.x * 32, ct = blockIdx.y;
  int i32 = lane & 31;
  int koff = (lane >> 5) << 3;
  const float inv = 1.f / 3200.f;

  // ---- stage slab: cols 0..255 BN(z), 256/257 coords, 258..319 zero
  {
    float sc[4], sh[4];
#pragma unroll
    for (int q = 0; q < 4; ++q) {
      int ch = lane * 4 + q;
      float mme = bnin[ch] * inv;
      float var = bnin[256 + ch] * inv - mme * mme;
      sc[q] = gamv[ch] * rsqrtf(var + 1e-5f);
      sh[q] = betv[ch] - mme * sc[q];
    }
#pragma unroll 4
    for (int s = 0; s < 32; ++s) {
      int m = r0 + s;
      float4 v = *(const float4*)(zin + (size_t)m * 256 + lane * 4);
      uint2 p;
      p.x = f2bf(v.x * sc[0] + sh[0]) | (f2bf(v.y * sc[1] + sh[1]) << 16);
      p.y = f2bf(v.z * sc[2] + sh[2]) | (f2bf(v.w * sc[3] + sh[3]) << 16);
      *(uint2*)(&slab[s * 328 + lane * 4]) = p;
    }
    // coords + zero tail: lane covers row s=lane&31, half=(lane>>5)*32 of cols 256..319
    int s = i32, half = (lane >> 5) * 32;
    int m = r0 + s, l = m % 100;
    float c0 = ((float)l * 0.1f - 2.0f) * 0.5f;
    float c1 = ((float)(l % 10) - 2.0f) * 0.5f;
#pragma unroll
    for (int seg = 0; seg < 4; ++seg) {
      uint4 z4; z4.x = z4.y = z4.z = z4.w = 0u;
      if (half == 0 && seg == 0) z4.x = f2bf(c0) | (f2bf(c1) << 16);
      *(uint4*)(&slab[s * 328 + 256 + half + seg * 8]) = z4;
    }
  }

  floatx16 acc0, acc1;
#pragma unroll
  for (int q = 0; q < 16; ++q) { acc0[q] = 0.f; acc1[q] = 0.f; }

  int brow = lane >> 3, bseg = (lane & 7) * 8;
  uint4 pre[8];
#pragma unroll
  for (int t = 0; t < 8; ++t)
    pre[t] = *(const uint4*)(wab + (size_t)(ct * 64 + t * 8 + brow) * 384 + bseg);

  for (int c = 0; c < 5; ++c) {
#pragma unroll
    for (int t = 0; t < 8; ++t)
      *(uint4*)(&Bs[(t * 8 + brow) * 72 + bseg]) = pre[t];
    if (c + 1 < 5) {
#pragma unroll
      for (int t = 0; t < 8; ++t)
        pre[t] = *(const uint4*)(wab + (size_t)(ct * 64 + t * 8 + brow) * 384 + (c + 1) * 64 + bseg);
    }
#pragma unroll
    for (int kk = 0; kk < 4; ++kk) {
      short8 a = *(const short8*)(&slab[i32 * 328 + c * 64 + kk * 16 + koff]);
      short8 b0 = *(const short8*)(&Bs[i32 * 72 + kk * 16 + koff]);
      short8 b1 = *(const short8*)(&Bs[(32 + i32) * 72 + kk * 16 + koff]);
      acc0 = __builtin_amdgcn_mfma_f32_32x32x16_bf16(a, b0, acc0, 0, 0, 0);
      acc1 = __builtin_amdgcn_mfma_f32_32x32x16_bf16(a, b1, acc1, 0, 0, 0);
    }
  }

  // ---- epilogue: ct<2 -> A half; ct>=2 -> C half (+hc), bf16 stores
#pragma unroll
  for (int nt = 0; nt < 2; ++nt) {
    int n = ct * 64 + nt * 32 + i32;
#pragma unroll
    for (int reg = 0; reg < 16; ++reg) {
      int rowp = (reg & 3) + 8 * (reg >> 2) + 4 * (lane >> 5);
      int m = r0 + rowp;
      float v = nt ? acc1[reg] : acc0[reg];
      if (ct < 2) {
        Abf[(size_t)m * 128 + n] = (unsigned short)f2bf(v);
      } else {
        int b = m / 100;
        int nc = n - 128;
        Cbf[(size_t)m * 128 + nc] = (unsigned short)f2bf(v + hc[b * 128 + nc]);
      }
    }
  }
}

// ---------------- fused relation MLP: col-split waves, all 3 layers' B in VGPRs
// block 256 thr = 4 waves; wave w owns cols [32w,32w+32); 2 tiles per block
__global__ __launch_bounds__(256, 2) void k_mlp(
    const unsigned short* __restrict__ Abf, const unsigned short* __restrict__ Cbf,
    const unsigned short* __restrict__ wmlp, const float* __restrict__ b2,
    const float* __restrict__ b3, const float* __restrict__ b4,
    float* __restrict__ sout) {
  __shared__ unsigned short gs[128 * 136];   // dword-stride 68 % 32 == 4 -> uniform banks
  int tid = threadIdx.x, lane = tid & 63, wave = tid >> 6;
  int ln31 = lane & 31;
  int koff = (lane >> 5) << 3;
  int col = wave * 32 + ln31;

  // persistent B fragments (coalesced: wmlp is in fragment order)
  short8 wreg[3][8];
#pragma unroll
  for (int z = 0; z < 3; ++z)
#pragma unroll
    for (int kk = 0; kk < 8; ++kk)
      wreg[z][kk] = *(const short8*)(wmlp + (size_t)(((z * 4 + wave) * 8 + kk) * 512) + lane * 8);
  float bv[3];
  bv[0] = b2[col]; bv[1] = b3[col]; bv[2] = b4[col];

  for (int ti = 0; ti < 2; ++ti) {
    int t = blockIdx.x + ti * 1264;
    int b = t / 79, tt = t - b * 79;
    __syncthreads();   // previous iteration's gs readers done
    {  // g0 = lrelu(C_i + A_j): wave builds its 32 rows, 2 lanes/row
      int lr = wave * 32 + (lane >> 1);
      int hh = lane & 1;
      int r = tt * 128 + lr;
      if (r > 9999) r = 9999;                  // clamp; masked at final sum
      const unsigned short* Crow = Cbf + (size_t)(b * 100 + r / 100) * 128;
      const unsigned short* Arow = Abf + (size_t)(b * 100 + r % 100) * 128;
#pragma unroll
      for (int it = 0; it < 8; ++it) {
        int cc = hh * 64 + it * 8;
        uint4 c4 = *(const uint4*)(Crow + cc);
        uint4 a4 = *(const uint4*)(Arow + cc);
        unsigned cw[4] = {c4.x, c4.y, c4.z, c4.w};
        unsigned aw[4] = {a4.x, a4.y, a4.z, a4.w};
        unsigned ow[4];
#pragma unroll
        for (int q = 0; q < 4; ++q) {
          float x0 = bits2f(cw[q] << 16) + bits2f(aw[q] << 16);
          float x1 = bits2f(cw[q] & 0xFFFF0000u) + bits2f(aw[q] & 0xFFFF0000u);
          x0 = fmaxf(x0, NEG * x0);
          x1 = fmaxf(x1, NEG * x1);
          ow[q] = f2bf(x0) | (f2bf(x1) << 16);
        }
        uint4 o4; o4.x = ow[0]; o4.y = ow[1]; o4.z = ow[2]; o4.w = ow[3];
        *(uint4*)(&gs[lr * 136 + cc]) = o4;
      }
    }
    __syncthreads();

    float colsum = 0.f;
#pragma unroll
    for (int z = 0; z < 3; ++z) {
      floatx16 acc[4];
#pragma unroll
      for (int rg = 0; rg < 4; ++rg)
#pragma unroll
        for (int q = 0; q < 16; ++q) acc[rg][q] = 0.f;
#pragma unroll
      for (int kk = 0; kk < 8; ++kk) {
#pragma unroll
        for (int rg = 0; rg < 4; ++rg) {
          short8 a = *(const short8*)(&gs[(rg * 32 + ln31) * 136 + kk * 16 + koff]);
          acc[rg] = __builtin_amdgcn_mfma_f32_32x32x16_bf16(a, wreg[z][kk], acc[rg], 0, 0, 0);
        }
      }
      if (z < 2) {
        __syncthreads();   // all waves done reading gs
#pragma unroll
        for (int rg = 0; rg < 4; ++rg)
#pragma unroll
          for (int reg = 0; reg < 16; ++reg) {
            int rowp = (reg & 3) + 8 * (reg >> 2) + 4 * (lane >> 5);
            float v = acc[rg][reg] + bv[z];
            v = fmaxf(v, NEG * v);
            gs[(rg * 32 + rowp) * 136 + col] = (unsigned short)f2bf(v);
          }
        __syncthreads();   // writes visible before next layer reads
      } else {
#pragma unroll
        for (int rg = 0; rg < 4; ++rg)
#pragma unroll
          for (int reg = 0; reg < 16; ++reg) {
            int rowp = (reg & 3) + 8 * (reg >> 2) + 4 * (lane >> 5);
            int p = tt * 128 + rg * 32 + rowp;
            float v = acc[rg][reg] + bv[2];
            v = fmaxf(v, NEG * v);
            colsum += (p < 10000) ? v : 0.f;
          }
      }
    }
    colsum += __shfl_xor(colsum, 32, 64);
    if (lane < 32) atomicAdd(&sout[b * 128 + wave * 32 + lane], colsum);
  }
}

// ---------------- final: out = lrelu(lrelu(s@F1+fb1)@F2+fb2), one block per b
__global__ void k_final(const float* __restrict__ s, const float* __restrict__ F1,
                        const float* __restrict__ fb1, const float* __restrict__ F2,
                        const float* __restrict__ fb2, float* __restrict__ out) {
  __shared__ float sl[128], t1[128];
  int b = blockIdx.x, t = threadIdx.x;
  if (t < 128) sl[t] = s[b * 128 + t];
  __syncthreads();
  if (t < 128) {
    float a = fb1[t];
    for (int k = 0; k < 128; ++k) a += sl[k] * F1[k * 128 + t];
    t1[t] = fmaxf(a, NEG * a);
  }
  __syncthreads();
  for (int o = t; o < 512; o += 256) {
    float a = fb2[o];
    for (int k = 0; k < 128; ++k) a += t1[k] * F2[k * 512 + o];
    out[b * 512 + o] = fmaxf(a, NEG * a);
  }
}

extern "C" void kernel_launch(void* const* d_in, const int* in_sizes, int n_in,
                              void* d_out, int out_size, void* d_ws, size_t ws_size,
                              hipStream_t stream) {
  const float* x   = (const float*)d_in[0];
  const float* h   = (const float*)d_in[1];
  const float* cw1 = (const float*)d_in[2];
  const float* cb1 = (const float*)d_in[3];
  const float* g1  = (const float*)d_in[4];
  const float* be1 = (const float*)d_in[5];
  const float* cw2 = (const float*)d_in[6];
  const float* cb2 = (const float*)d_in[7];
  const float* g2  = (const float*)d_in[8];
  const float* be2 = (const float*)d_in[9];
  const float* cw3 = (const float*)d_in[10];
  const float* cb3 = (const float*)d_in[11];
  const float* g3  = (const float*)d_in[12];
  const float* be3 = (const float*)d_in[13];
  const float* cw4 = (const float*)d_in[14];
  const float* cb4 = (const float*)d_in[15];
  const float* g4  = (const float*)d_in[16];
  const float* be4 = (const float*)d_in[17];
  const float* W1  = (const float*)d_in[18];
  const float* b1  = (const float*)d_in[19];
  const float* W2  = (const float*)d_in[20];
  const float* b2  = (const float*)d_in[21];
  const float* W3  = (const float*)d_in[22];
  const float* b3  = (const float*)d_in[23];
  const float* W4  = (const float*)d_in[24];
  const float* b4  = (const float*)d_in[25];
  const float* F1  = (const float*)d_in[26];
  const float* fb1 = (const float*)d_in[27];
  const float* F2  = (const float*)d_in[28];
  const float* fb2 = (const float*)d_in[29];

  char* ws = (char*)d_ws;
  float* bn0  = (float*)(ws + 0);
  float* bn1  = (float*)(ws + 2048);
  float* bn2  = (float*)(ws + 4096);
  float* bn3  = (float*)(ws + 6144);
  float* sbuf = (float*)(ws + 8192);                        // 32x128 fp32
  float* za   = (float*)(ws + 24576);                       // 3200x256 fp32
  float* zb   = (float*)(ws + 3301376);                     // 3200x256 fp32
  unsigned short* wt1  = (unsigned short*)(ws + 6578176);   // 256x1536 bf16
  unsigned short* wt2  = (unsigned short*)(ws + 7364608);   // 256x768
  unsigned short* wt3  = (unsigned short*)(ws + 7757824);
  unsigned short* wt4  = (unsigned short*)(ws + 8151040);
  unsigned short* wab  = (unsigned short*)(ws + 8544256);   // 256x384
  unsigned short* wmlp = (unsigned short*)(ws + 8740864);   // 3x16384 frag-order
  unsigned short* Abf  = (unsigned short*)(ws + 8839168);   // 3200x128 bf16
  unsigned short* Cbf  = (unsigned short*)(ws + 9658368);   // 3200x128 bf16
  float* hc   = (float*)(ws + 10477568);                    // 32x128 fp32; end 10493952

  hipMemsetAsync(d_ws, 0, 24576, stream);     // bn sums + s accumulator

  k_prep<<<1888, 256, 0, stream>>>(cw1, cw2, cw3, cw4, wt1, wt2, wt3, wt4,
                                   W1, wab, W2, W3, W4, wmlp, h, b1, hc);

  const int lds1 = (34 * 520 + 64 * 72) * 2;   // 44576 B
  const int lds2 = (34 * 264 + 64 * 72) * 2;   // 27168 B
  k_conv<<<dim3(100, 4), 64, lds1, stream>>>(x,  nullptr, nullptr, nullptr, wt1, cb1, za, bn0, 512, 1);
  k_conv<<<dim3(100, 4), 64, lds2, stream>>>(za, bn0, g1, be1, wt2, cb2, zb, bn1, 256, 0);
  k_conv<<<dim3(100, 4), 64, lds2, stream>>>(zb, bn1, g2, be2, wt3, cb3, za, bn2, 256, 0);
  k_conv<<<dim3(100, 4), 64, lds2, stream>>>(za, bn2, g3, be3, wt4, cb4, zb, bn3, 256, 0);

  k_ac<<<dim3(100, 4), 64, 0, stream>>>(zb, bn3, g4, be4, wab, hc, Abf, Cbf);

  k_mlp<<<1264, 256, 0, stream>>>(Abf, Cbf, wmlp, b2, b3, b4, sbuf);
  k_final<<<32, 256, 0, stream>>>(sbuf, F1, fb1, F2, fb2, (float*)d_out);
}

// Round 4
// 308.549 us; speedup vs baseline: 1.3039x; 1.1770x over previous
//
#include <hip/hip_runtime.h>
#include <stdint.h>
#include <stddef.h>

#define NEG 0.1f

typedef __attribute__((ext_vector_type(8))) short short8;
typedef __attribute__((ext_vector_type(16))) float floatx16;

__device__ __forceinline__ unsigned f2bf(float f) {
  union { float f; unsigned u; } v; v.f = f;
  unsigned r = v.u + 0x7FFFu + ((v.u >> 16) & 1u);   // RNE
  return r >> 16;
}
__device__ __forceinline__ float bits2f(unsigned u) {
  union { unsigned u; float f; } v; v.u = u; return v.f;
}

// ---------------- fused prep: conv-w bf16 | wab (LDS transpose) | wmlp | hc (k-split)
__global__ void k_prep(const float* __restrict__ cw1, const float* __restrict__ cw2,
                       const float* __restrict__ cw3, const float* __restrict__ cw4,
                       unsigned short* __restrict__ wt1, unsigned short* __restrict__ wt2,
                       unsigned short* __restrict__ wt3, unsigned short* __restrict__ wt4,
                       const float* __restrict__ W1, unsigned short* __restrict__ wab,
                       const float* __restrict__ W2, const float* __restrict__ W3,
                       const float* __restrict__ W4, unsigned short* __restrict__ wmlp,
                       const float* __restrict__ h, float* __restrict__ hc) {
  __shared__ float tile[64 * 65];
  int bid = blockIdx.x, tid = threadIdx.x;
  if (bid < 1280) {                       // conv weights: Wt[f][ks*E+e] = cw[f][e][ks]
    int z = bid;
    int E; const float* cw; unsigned short* wt;
    if (z < 512) { E = 512; cw = cw1; wt = wt1; }
    else {
      int q = (z - 512) >> 8; E = 256;
      cw = (q == 0) ? cw2 : ((q == 1) ? cw3 : cw4);
      wt = (q == 0) ? wt2 : ((q == 1) ? wt3 : wt4);
      z = (z - 512) & 255;
    }
    int idx = z * 256 + tid;              // over F*E
    int f = idx / E, e = idx - f * E;
    const float* s = cw + (size_t)idx * 3;
    unsigned short* d = wt + (size_t)f * 3 * E + e;
    d[0] = (unsigned short)f2bf(s[0]);
    d[E] = (unsigned short)f2bf(s[1]);
    d[2 * E] = (unsigned short)f2bf(s[2]);
  } else if (bid < 1304) {                // wab via LDS transpose: wab[n][kp]=W1[d][n&127]
    int tw = bid - 1280;                  // 24 tiles: half(2) x dt(6) x nt(2)
    int half = tw / 12, rem = tw % 12, dt = rem >> 1, nt = rem & 1;
    int c = tid & 63, rq = tid >> 6;
    // read: rows kp_local = rq+4*it, cols n127 = nt*64+c (coalesced)
#pragma unroll
    for (int it = 0; it < 16; ++it) {
      int r = rq + it * 4;
      int kp = dt * 64 + r;
      float v = 0.f;
      if (kp < 258) v = W1[(size_t)(half * 258 + kp) * 128 + nt * 64 + c];
      tile[r * 65 + c] = v;
    }
    __syncthreads();
    // write: wab[(half*128+nt*64+r2)*384 + dt*64 + c2], c2 fast (coalesced)
#pragma unroll
    for (int it = 0; it < 16; ++it) {
      int r2 = rq + it * 4;
      wab[(size_t)(half * 128 + nt * 64 + r2) * 384 + dt * 64 + c] =
          (unsigned short)f2bf(tile[c * 65 + r2]);
    }
  } else if (bid < 1496) {                // wmlp frag-order, reads coalesced over n
    int i2 = (bid - 1304) * 256 + tid;    // z(3) x k(128) x n(128)
    int n = i2 & 127, k = (i2 >> 7) & 127, zz = i2 >> 14;
    const float* W = (zz == 0) ? W2 : ((zz == 1) ? W3 : W4);
    float v = W[k * 128 + n];
    int w = n >> 5, l = ((k >> 3) & 1) * 32 + (n & 31), kk = k >> 4, j = k & 7;
    int i = (((zz * 4 + w) * 8 + kk) << 9) | (l << 3) | j;
    wmlp[i] = (unsigned short)f2bf(v);
  } else {                                // hc partial: 128 blocks = b(32) x seg(4)
    int t = bid - 1496;
    int b = t >> 2, seg = t & 3;
    int m = tid & 127, sub = tid >> 7;
    int k0 = seg * 128 + sub * 64;
    const float* hr = h + b * 512 + k0;
    const float* Wc = W1 + (size_t)(516 + k0) * 128 + m;
    float a0 = 0.f, a1 = 0.f, a2 = 0.f, a3 = 0.f, a4 = 0.f, a5 = 0.f, a6 = 0.f, a7 = 0.f;
#pragma unroll
    for (int k = 0; k < 64; k += 8) {
      a0 += hr[k + 0] * Wc[(size_t)(k + 0) * 128];
      a1 += hr[k + 1] * Wc[(size_t)(k + 1) * 128];
      a2 += hr[k + 2] * Wc[(size_t)(k + 2) * 128];
      a3 += hr[k + 3] * Wc[(size_t)(k + 3) * 128];
      a4 += hr[k + 4] * Wc[(size_t)(k + 4) * 128];
      a5 += hr[k + 5] * Wc[(size_t)(k + 5) * 128];
      a6 += hr[k + 6] * Wc[(size_t)(k + 6) * 128];
      a7 += hr[k + 7] * Wc[(size_t)(k + 7) * 128];
    }
    float s = ((a0 + a1) + (a2 + a3)) + ((a4 + a5) + (a6 + a7));
    atomicAdd(&hc[b * 128 + m], s);
  }
}

// ---------------- conv (implicit im2col + fused input-BN + epilogue BN-sums)
// grid (100,4), 64 threads. Tile: 32 rows x 64 f-cols. K = 3*E, chunks of 64.
__global__ __launch_bounds__(64, 2) void k_conv(
    const float* __restrict__ zin, const float* __restrict__ bnin,
    const float* __restrict__ gamv, const float* __restrict__ betv,
    const unsigned short* __restrict__ wt, const float* __restrict__ cb,
    float* __restrict__ zout, float* __restrict__ bnout, int E, int xmode) {
  extern __shared__ unsigned short smem[];
  const int SL = (E == 512) ? 520 : 264;     // slab stride (shorts), dword-stride % 32 == 4
  unsigned short* slab = smem;               // 34 x SL
  unsigned short* Bs = smem + 34 * SL;       // 64 x 72
  const int K = 3 * E, NC = K >> 6;
  const int esh = (E == 512) ? 9 : 8;
  int lane = threadIdx.x;
  int r0 = blockIdx.x * 32, ct = blockIdx.y;
  int i32 = lane & 31;
  int koff = (lane >> 5) << 3;

  // validity per ks for this lane's tile-row
  int lrow = (r0 + i32) % 100;
  bool vks0 = (lrow >= 1), vks2 = (lrow <= 98);

  // ---- stage input slab (rows m = r0-1 .. r0+32, clamped; garbage rows masked later)
  if (xmode) {  // conv1: read x (L,B,E) layout, no BN, E=512
#pragma unroll 2
    for (int s = 0; s < 34; ++s) {
      int m = r0 - 1 + s; m = min(max(m, 0), 3199);
      int b = m / 100, l = m - b * 100;
      size_t base = (size_t)(l * 32 + b) * 512;
#pragma unroll
      for (int cc = 0; cc < 2; ++cc) {
        int ch = cc * 256 + lane * 4;
        float4 v = *(const float4*)(zin + base + ch);
        uint2 p;
        p.x = f2bf(v.x) | (f2bf(v.y) << 16);
        p.y = f2bf(v.z) | (f2bf(v.w) << 16);
        *(uint2*)(&slab[s * SL + ch]) = p;
      }
    }
  } else {      // convs 2-4: read z (m,256) layout with BN applied
    const float inv = 1.f / 3200.f;
    float sc[4], sh[4];
#pragma unroll
    for (int q = 0; q < 4; ++q) {
      int ch = lane * 4 + q;
      float mme = bnin[ch] * inv;
      float var = bnin[256 + ch] * inv - mme * mme;
      sc[q] = gamv[ch] * rsqrtf(var + 1e-5f);
      sh[q] = betv[ch] - mme * sc[q];
    }
#pragma unroll 4
    for (int s = 0; s < 34; ++s) {
      int m = r0 - 1 + s; m = min(max(m, 0), 3199);
      float4 v = *(const float4*)(zin + (size_t)m * 256 + lane * 4);
      uint2 p;
      p.x = f2bf(v.x * sc[0] + sh[0]) | (f2bf(v.y * sc[1] + sh[1]) << 16);
      p.y = f2bf(v.z * sc[2] + sh[2]) | (f2bf(v.w * sc[3] + sh[3]) << 16);
      *(uint2*)(&slab[s * SL + lane * 4]) = p;
    }
  }

  floatx16 acc0, acc1;
#pragma unroll
  for (int q = 0; q < 16; ++q) { acc0[q] = 0.f; acc1[q] = 0.f; }

  // ---- K loop over 64-wide chunks; B chunk staged in LDS w/ register prefetch
  int brow = lane >> 3, bseg = (lane & 7) * 8;
  uint4 pre[8];
#pragma unroll
  for (int t = 0; t < 8; ++t)
    pre[t] = *(const uint4*)(wt + (size_t)(ct * 64 + t * 8 + brow) * K + bseg);

  for (int c = 0; c < NC; ++c) {
#pragma unroll
    for (int t = 0; t < 8; ++t)
      *(uint4*)(&Bs[(t * 8 + brow) * 72 + bseg]) = pre[t];
    if (c + 1 < NC) {
#pragma unroll
      for (int t = 0; t < 8; ++t)
        pre[t] = *(const uint4*)(wt + (size_t)(ct * 64 + t * 8 + brow) * K + (c + 1) * 64 + bseg);
    }
    int ks = (c << 6) >> esh;
    int ebase = (c << 6) & (E - 1);
    bool v = (ks == 0) ? vks0 : ((ks == 2) ? vks2 : true);
    int srow = i32 + ks;
#pragma unroll
    for (int kk = 0; kk < 4; ++kk) {
      short8 a = {};
      if (v) a = *(const short8*)(&slab[srow * SL + ebase + kk * 16 + koff]);
      short8 b0 = *(const short8*)(&Bs[i32 * 72 + kk * 16 + koff]);
      short8 b1 = *(const short8*)(&Bs[(32 + i32) * 72 + kk * 16 + koff]);
      acc0 = __builtin_amdgcn_mfma_f32_32x32x16_bf16(a, b0, acc0, 0, 0, 0);
      acc1 = __builtin_amdgcn_mfma_f32_32x32x16_bf16(a, b1, acc1, 0, 0, 0);
    }
  }

  // ---- epilogue: bias + lrelu, store z fp32, BN sum/sumsq atomics
#pragma unroll
  for (int nt = 0; nt < 2; ++nt) {
    int f = ct * 64 + nt * 32 + i32;
    float bias = cb[f];
    float s1 = 0.f, s2 = 0.f;
#pragma unroll
    for (int reg = 0; reg < 16; ++reg) {
      int rowp = (reg & 3) + 8 * (reg >> 2) + 4 * (lane >> 5);
      int m = r0 + rowp;
      float v = (nt ? acc1[reg] : acc0[reg]) + bias;
      v = fmaxf(v, NEG * v);
      zout[(size_t)m * 256 + f] = v;
      s1 += v; s2 += v * v;
    }
    s1 += __shfl_xor(s1, 32, 64);
    s2 += __shfl_xor(s2, 32, 64);
    if (lane < 32) { atomicAdd(&bnout[f], s1); atomicAdd(&bnout[256 + f], s2); }
  }
}

// ---------------- A/C GEMM w/ fused BN4 + coords (implicit xf build)
// grid (100,4), 64 threads. Tile 32 rows x 64 n-cols, K padded to 320.
__global__ __launch_bounds__(64, 2) void k_ac(
    const float* __restrict__ zin, const float* __restrict__ bnin,
    const float* __restrict__ gamv, const float* __restrict__ betv,
    const unsigned short* __restrict__ wab, const float* __restrict__ hc,
    const float* __restrict__ b1v,
    unsigned short* __restrict__ Abf, unsigned short* __restrict__ Cbf) {
  __shared__ unsigned short slab[32 * 328];   // stride 328: dword-stride % 32 == 4
  __shared__ unsigned short Bs[64 * 72];
  int lane = threadIdx.x;
  int r0 = blockIdx.x * 32, ct = blockIdx.y;
  int i32 = lane & 31;
  int koff = (lane >> 5) << 3;
  const float inv = 1.f / 3200.f;

  // ---- stage slab: cols 0..255 BN(z), 256/257 coords, 258..319 zero
  {
    float sc[4], sh[4];
#pragma unroll
    for (int q = 0; q < 4; ++q) {
      int ch = lane * 4 + q;
      float mme = bnin[ch] * inv;
      float var = bnin[256 + ch] * inv - mme * mme;
      sc[q] = gamv[ch] * rsqrtf(var + 1e-5f);
      sh[q] = betv[ch] - mme * sc[q];
    }
#pragma unroll 4
    for (int s = 0; s < 32; ++s) {
      int m = r0 + s;
      float4 v = *(const float4*)(zin + (size_t)m * 256 + lane * 4);
      uint2 p;
      p.x = f2bf(v.x * sc[0] + sh[0]) | (f2bf(v.y * sc[1] + sh[1]) << 16);
      p.y = f2bf(v.z * sc[2] + sh[2]) | (f2bf(v.w * sc[3] + sh[3]) << 16);
      *(uint2*)(&slab[s * 328 + lane * 4]) = p;
    }
    // coords + zero tail: lane covers row s=lane&31, half=(lane>>5)*32 of cols 256..319
    int s = i32, half = (lane >> 5) * 32;
    int m = r0 + s, l = m % 100;
    float c0 = ((float)l * 0.1f - 2.0f) * 0.5f;
    float c1 = ((float)(l % 10) - 2.0f) * 0.5f;
#pragma unroll
    for (int seg = 0; seg < 4; ++seg) {
      uint4 z4; z4.x = z4.y = z4.z = z4.w = 0u;
      if (half == 0 && seg == 0) z4.x = f2bf(c0) | (f2bf(c1) << 16);
      *(uint4*)(&slab[s * 328 + 256 + half + seg * 8]) = z4;
    }
  }

  floatx16 acc0, acc1;
#pragma unroll
  for (int q = 0; q < 16; ++q) { acc0[q] = 0.f; acc1[q] = 0.f; }

  int brow = lane >> 3, bseg = (lane & 7) * 8;
  uint4 pre[8];
#pragma unroll
  for (int t = 0; t < 8; ++t)
    pre[t] = *(const uint4*)(wab + (size_t)(ct * 64 + t * 8 + brow) * 384 + bseg);

  for (int c = 0; c < 5; ++c) {
#pragma unroll
    for (int t = 0; t < 8; ++t)
      *(uint4*)(&Bs[(t * 8 + brow) * 72 + bseg]) = pre[t];
    if (c + 1 < 5) {
#pragma unroll
      for (int t = 0; t < 8; ++t)
        pre[t] = *(const uint4*)(wab + (size_t)(ct * 64 + t * 8 + brow) * 384 + (c + 1) * 64 + bseg);
    }
#pragma unroll
    for (int kk = 0; kk < 4; ++kk) {
      short8 a = *(const short8*)(&slab[i32 * 328 + c * 64 + kk * 16 + koff]);
      short8 b0 = *(const short8*)(&Bs[i32 * 72 + kk * 16 + koff]);
      short8 b1 = *(const short8*)(&Bs[(32 + i32) * 72 + kk * 16 + koff]);
      acc0 = __builtin_amdgcn_mfma_f32_32x32x16_bf16(a, b0, acc0, 0, 0, 0);
      acc1 = __builtin_amdgcn_mfma_f32_32x32x16_bf16(a, b1, acc1, 0, 0, 0);
    }
  }

  // ---- epilogue: ct<2 -> A half; ct>=2 -> C half (+hc+b1), bf16 stores
#pragma unroll
  for (int nt = 0; nt < 2; ++nt) {
    int n = ct * 64 + nt * 32 + i32;
#pragma unroll
    for (int reg = 0; reg < 16; ++reg) {
      int rowp = (reg & 3) + 8 * (reg >> 2) + 4 * (lane >> 5);
      int m = r0 + rowp;
      float v = nt ? acc1[reg] : acc0[reg];
      if (ct < 2) {
        Abf[(size_t)m * 128 + n] = (unsigned short)f2bf(v);
      } else {
        int b = m / 100;
        int nc = n - 128;
        Cbf[(size_t)m * 128 + nc] =
            (unsigned short)f2bf(v + hc[b * 128 + nc] + b1v[nc]);
      }
    }
  }
}

// ---------------- fused relation MLP: col-split waves, all 3 layers' B in VGPRs
// block 256 thr = 4 waves; wave w owns cols [32w,32w+32); 2 tiles per block
__global__ __launch_bounds__(256, 2) void k_mlp(
    const unsigned short* __restrict__ Abf, const unsigned short* __restrict__ Cbf,
    const unsigned short* __restrict__ wmlp, const float* __restrict__ b2,
    const float* __restrict__ b3, const float* __restrict__ b4,
    float* __restrict__ sout) {
  __shared__ unsigned short gs[128 * 136];   // dword-stride 68 % 32 == 4 -> uniform banks
  int tid = threadIdx.x, lane = tid & 63, wave = tid >> 6;
  int ln31 = lane & 31;
  int koff = (lane >> 5) << 3;
  int col = wave * 32 + ln31;

  // persistent B fragments (coalesced: wmlp is in fragment order)
  short8 wreg[3][8];
#pragma unroll
  for (int z = 0; z < 3; ++z)
#pragma unroll
    for (int kk = 0; kk < 8; ++kk)
      wreg[z][kk] = *(const short8*)(wmlp + (size_t)(((z * 4 + wave) * 8 + kk) * 512) + lane * 8);
  float bv[3];
  bv[0] = b2[col]; bv[1] = b3[col]; bv[2] = b4[col];

  for (int ti = 0; ti < 2; ++ti) {
    int t = blockIdx.x + ti * 1264;
    int b = t / 79, tt = t - b * 79;
    __syncthreads();   // previous iteration's gs readers done
    {  // g0 = lrelu(C_i + A_j): wave builds its 32 rows, 2 lanes/row
      int lr = wave * 32 + (lane >> 1);
      int hh = lane & 1;
      int r = tt * 128 + lr;
      if (r > 9999) r = 9999;                  // clamp; masked at final sum
      const unsigned short* Crow = Cbf + (size_t)(b * 100 + r / 100) * 128;
      const unsigned short* Arow = Abf + (size_t)(b * 100 + r % 100) * 128;
#pragma unroll
      for (int it = 0; it < 8; ++it) {
        int cc = hh * 64 + it * 8;
        uint4 c4 = *(const uint4*)(Crow + cc);
        uint4 a4 = *(const uint4*)(Arow + cc);
        unsigned cw[4] = {c4.x, c4.y, c4.z, c4.w};
        unsigned aw[4] = {a4.x, a4.y, a4.z, a4.w};
        unsigned ow[4];
#pragma unroll
        for (int q = 0; q < 4; ++q) {
          float x0 = bits2f(cw[q] << 16) + bits2f(aw[q] << 16);
          float x1 = bits2f(cw[q] & 0xFFFF0000u) + bits2f(aw[q] & 0xFFFF0000u);
          x0 = fmaxf(x0, NEG * x0);
          x1 = fmaxf(x1, NEG * x1);
          ow[q] = f2bf(x0) | (f2bf(x1) << 16);
        }
        uint4 o4; o4.x = ow[0]; o4.y = ow[1]; o4.z = ow[2]; o4.w = ow[3];
        *(uint4*)(&gs[lr * 136 + cc]) = o4;
      }
    }
    __syncthreads();

    float colsum = 0.f;
#pragma unroll
    for (int z = 0; z < 3; ++z) {
      floatx16 acc[4];
#pragma unroll
      for (int rg = 0; rg < 4; ++rg)
#pragma unroll
        for (int q = 0; q < 16; ++q) acc[rg][q] = 0.f;
#pragma unroll
      for (int kk = 0; kk < 8; ++kk) {
#pragma unroll
        for (int rg = 0; rg < 4; ++rg) {
          short8 a = *(const short8*)(&gs[(rg * 32 + ln31) * 136 + kk * 16 + koff]);
          acc[rg] = __builtin_amdgcn_mfma_f32_32x32x16_bf16(a, wreg[z][kk], acc[rg], 0, 0, 0);
        }
      }
      if (z < 2) {
        __syncthreads();   // all waves done reading gs
#pragma unroll
        for (int rg = 0; rg < 4; ++rg)
#pragma unroll
          for (int reg = 0; reg < 16; ++reg) {
            int rowp = (reg & 3) + 8 * (reg >> 2) + 4 * (lane >> 5);
            float v = acc[rg][reg] + bv[z];
            v = fmaxf(v, NEG * v);
            gs[(rg * 32 + rowp) * 136 + col] = (unsigned short)f2bf(v);
          }
        __syncthreads();   // writes visible before next layer reads
      } else {
#pragma unroll
        for (int rg = 0; rg < 4; ++rg)
#pragma unroll
          for (int reg = 0; reg < 16; ++reg) {
            int rowp = (reg & 3) + 8 * (reg >> 2) + 4 * (lane >> 5);
            int p = tt * 128 + rg * 32 + rowp;
            float v = acc[rg][reg] + bv[2];
            v = fmaxf(v, NEG * v);
            colsum += (p < 10000) ? v : 0.f;
          }
      }
    }
    colsum += __shfl_xor(colsum, 32, 64);
    if (lane < 32) atomicAdd(&sout[b * 128 + wave * 32 + lane], colsum);
  }
}

// ---------------- final: out = lrelu(lrelu(s@F1+fb1)@F2+fb2), one block per b
__global__ void k_final(const float* __restrict__ s, const float* __restrict__ F1,
                        const float* __restrict__ fb1, const float* __restrict__ F2,
                        const float* __restrict__ fb2, float* __restrict__ out) {
  __shared__ float sl[128], t1[128];
  int b = blockIdx.x, t = threadIdx.x;
  if (t < 128) sl[t] = s[b * 128 + t];
  __syncthreads();
  if (t < 128) {
    float a = fb1[t];
    for (int k = 0; k < 128; ++k) a += sl[k] * F1[k * 128 + t];
    t1[t] = fmaxf(a, NEG * a);
  }
  __syncthreads();
  for (int o = t; o < 512; o += 256) {
    float a = fb2[o];
    for (int k = 0; k < 128; ++k) a += t1[k] * F2[k * 512 + o];
    out[b * 512 + o] = fmaxf(a, NEG * a);
  }
}

extern "C" void kernel_launch(void* const* d_in, const int* in_sizes, int n_in,
                              void* d_out, int out_size, void* d_ws, size_t ws_size,
                              hipStream_t stream) {
  const float* x   = (const float*)d_in[0];
  const float* h   = (const float*)d_in[1];
  const float* cw1 = (const float*)d_in[2];
  const float* cb1 = (const float*)d_in[3];
  const float* g1  = (const float*)d_in[4];
  const float* be1 = (const float*)d_in[5];
  const float* cw2 = (const float*)d_in[6];
  const float* cb2 = (const float*)d_in[7];
  const float* g2  = (const float*)d_in[8];
  const float* be2 = (const float*)d_in[9];
  const float* cw3 = (const float*)d_in[10];
  const float* cb3 = (const float*)d_in[11];
  const float* g3  = (const float*)d_in[12];
  const float* be3 = (const float*)d_in[13];
  const float* cw4 = (const float*)d_in[14];
  const float* cb4 = (const float*)d_in[15];
  const float* g4  = (const float*)d_in[16];
  const float* be4 = (const float*)d_in[17];
  const float* W1  = (const float*)d_in[18];
  const float* b1  = (const float*)d_in[19];
  const float* W2  = (const float*)d_in[20];
  const float* b2  = (const float*)d_in[21];
  const float* W3  = (const float*)d_in[22];
  const float* b3  = (const float*)d_in[23];
  const float* W4  = (const float*)d_in[24];
  const float* b4  = (const float*)d_in[25];
  const float* F1  = (const float*)d_in[26];
  const float* fb1 = (const float*)d_in[27];
  const float* F2  = (const float*)d_in[28];
  const float* fb2 = (const float*)d_in[29];

  char* ws = (char*)d_ws;
  float* bn0  = (float*)(ws + 0);
  float* bn1  = (float*)(ws + 2048);
  float* bn2  = (float*)(ws + 4096);
  float* bn3  = (float*)(ws + 6144);
  float* sbuf = (float*)(ws + 8192);                        // 32x128 fp32
  float* hc   = (float*)(ws + 24576);                       // 32x128 fp32 (zeroed)
  float* za   = (float*)(ws + 40960);                       // 3200x256 fp32
  float* zb   = (float*)(ws + 3317760);                     // 3200x256 fp32
  unsigned short* wt1  = (unsigned short*)(ws + 6594560);   // 256x1536 bf16
  unsigned short* wt2  = (unsigned short*)(ws + 7380992);   // 256x768
  unsigned short* wt3  = (unsigned short*)(ws + 7774208);
  unsigned short* wt4  = (unsigned short*)(ws + 8167424);
  unsigned short* wab  = (unsigned short*)(ws + 8560640);   // 256x384
  unsigned short* wmlp = (unsigned short*)(ws + 8757248);   // 3x16384 frag-order
  unsigned short* Abf  = (unsigned short*)(ws + 8855552);   // 3200x128 bf16
  unsigned short* Cbf  = (unsigned short*)(ws + 9674752);   // 3200x128 bf16; end 10493952

  hipMemsetAsync(d_ws, 0, 40960, stream);     // bn sums + s accumulator + hc

  k_prep<<<1624, 256, 0, stream>>>(cw1, cw2, cw3, cw4, wt1, wt2, wt3, wt4,
                                   W1, wab, W2, W3, W4, wmlp, h, hc);

  const int lds1 = (34 * 520 + 64 * 72) * 2;   // 44576 B
  const int lds2 = (34 * 264 + 64 * 72) * 2;   // 27168 B
  k_conv<<<dim3(100, 4), 64, lds1, stream>>>(x,  nullptr, nullptr, nullptr, wt1, cb1, za, bn0, 512, 1);
  k_conv<<<dim3(100, 4), 64, lds2, stream>>>(za, bn0, g1, be1, wt2, cb2, zb, bn1, 256, 0);
  k_conv<<<dim3(100, 4), 64, lds2, stream>>>(zb, bn1, g2, be2, wt3, cb3, za, bn2, 256, 0);
  k_conv<<<dim3(100, 4), 64, lds2, stream>>>(za, bn2, g3, be3, wt4, cb4, zb, bn3, 256, 0);

  k_ac<<<dim3(100, 4), 64, 0, stream>>>(zb, bn3, g4, be4, wab, hc, b1, Abf, Cbf);

  k_mlp<<<1264, 256, 0, stream>>>(Abf, Cbf, wmlp, b2, b3, b4, sbuf);
  k_final<<<32, 256, 0, stream>>>(sbuf, F1, fb1, F2, fb2, (float*)d_out);
}

// Round 5
// 292.252 us; speedup vs baseline: 1.3766x; 1.0558x over previous
//
#include <hip/hip_runtime.h>
#include <hip/hip_bf16.h>
#include <stdint.h>
#include <stddef.h>

#define NEG 0.1f

typedef __attribute__((ext_vector_type(8))) short short8;
typedef __attribute__((ext_vector_type(16))) float floatx16;

__device__ __forceinline__ unsigned f2bf(float f) {
  union { float f; unsigned u; } v; v.f = f;
  unsigned r = v.u + 0x7FFFu + ((v.u >> 16) & 1u);   // RNE
  return r >> 16;
}
__device__ __forceinline__ unsigned pk2bf(float a, float b) {   // a -> low16, b -> high16
  __hip_bfloat162 h = __float22bfloat162_rn(make_float2(a, b));
  union { __hip_bfloat162 h; unsigned u; } v; v.h = h; return v.u;
}
__device__ __forceinline__ float bits2f(unsigned u) {
  union { unsigned u; float f; } v; v.u = u; return v.f;
}

// ---------------- fused prep: conv-w bf16 | wab (LDS transpose) | wmlp | hc (k-split)
__global__ void k_prep(const float* __restrict__ cw1, const float* __restrict__ cw2,
                       const float* __restrict__ cw3, const float* __restrict__ cw4,
                       unsigned short* __restrict__ wt1, unsigned short* __restrict__ wt2,
                       unsigned short* __restrict__ wt3, unsigned short* __restrict__ wt4,
                       const float* __restrict__ W1, unsigned short* __restrict__ wab,
                       const float* __restrict__ W2, const float* __restrict__ W3,
                       const float* __restrict__ W4, unsigned short* __restrict__ wmlp,
                       const float* __restrict__ h, float* __restrict__ hc) {
  __shared__ float tile[64 * 65];
  int bid = blockIdx.x, tid = threadIdx.x;
  if (bid < 1280) {                       // conv weights: Wt[f][ks*E+e] = cw[f][e][ks]
    int z = bid;
    int E; const float* cw; unsigned short* wt;
    if (z < 512) { E = 512; cw = cw1; wt = wt1; }
    else {
      int q = (z - 512) >> 8; E = 256;
      cw = (q == 0) ? cw2 : ((q == 1) ? cw3 : cw4);
      wt = (q == 0) ? wt2 : ((q == 1) ? wt3 : wt4);
      z = (z - 512) & 255;
    }
    int idx = z * 256 + tid;              // over F*E
    int f = idx / E, e = idx - f * E;
    const float* s = cw + (size_t)idx * 3;
    unsigned short* d = wt + (size_t)f * 3 * E + e;
    d[0] = (unsigned short)f2bf(s[0]);
    d[E] = (unsigned short)f2bf(s[1]);
    d[2 * E] = (unsigned short)f2bf(s[2]);
  } else if (bid < 1304) {                // wab via LDS transpose: wab[n][kp]=W1[d][n&127]
    int tw = bid - 1280;                  // 24 tiles: half(2) x dt(6) x nt(2)
    int half = tw / 12, rem = tw % 12, dt = rem >> 1, nt = rem & 1;
    int c = tid & 63, rq = tid >> 6;
#pragma unroll
    for (int it = 0; it < 16; ++it) {
      int r = rq + it * 4;
      int kp = dt * 64 + r;
      float v = 0.f;
      if (kp < 258) v = W1[(size_t)(half * 258 + kp) * 128 + nt * 64 + c];
      tile[r * 65 + c] = v;
    }
    __syncthreads();
#pragma unroll
    for (int it = 0; it < 16; ++it) {
      int r2 = rq + it * 4;
      wab[(size_t)(half * 128 + nt * 64 + r2) * 384 + dt * 64 + c] =
          (unsigned short)f2bf(tile[c * 65 + r2]);
    }
  } else if (bid < 1496) {                // wmlp frag-order, reads coalesced over n
    int i2 = (bid - 1304) * 256 + tid;    // z(3) x k(128) x n(128)
    int n = i2 & 127, k = (i2 >> 7) & 127, zz = i2 >> 14;
    const float* W = (zz == 0) ? W2 : ((zz == 1) ? W3 : W4);
    float v = W[k * 128 + n];
    int w = n >> 5, l = ((k >> 3) & 1) * 32 + (n & 31), kk = k >> 4, j = k & 7;
    int i = (((zz * 4 + w) * 8 + kk) << 9) | (l << 3) | j;
    wmlp[i] = (unsigned short)f2bf(v);
  } else {                                // hc partial: 128 blocks = b(32) x seg(4)
    int t = bid - 1496;
    int b = t >> 2, seg = t & 3;
    int m = tid & 127, sub = tid >> 7;
    int k0 = seg * 128 + sub * 64;
    const float* hr = h + b * 512 + k0;
    const float* Wc = W1 + (size_t)(516 + k0) * 128 + m;
    float a0 = 0.f, a1 = 0.f, a2 = 0.f, a3 = 0.f, a4 = 0.f, a5 = 0.f, a6 = 0.f, a7 = 0.f;
#pragma unroll
    for (int k = 0; k < 64; k += 8) {
      a0 += hr[k + 0] * Wc[(size_t)(k + 0) * 128];
      a1 += hr[k + 1] * Wc[(size_t)(k + 1) * 128];
      a2 += hr[k + 2] * Wc[(size_t)(k + 2) * 128];
      a3 += hr[k + 3] * Wc[(size_t)(k + 3) * 128];
      a4 += hr[k + 4] * Wc[(size_t)(k + 4) * 128];
      a5 += hr[k + 5] * Wc[(size_t)(k + 5) * 128];
      a6 += hr[k + 6] * Wc[(size_t)(k + 6) * 128];
      a7 += hr[k + 7] * Wc[(size_t)(k + 7) * 128];
    }
    float s = ((a0 + a1) + (a2 + a3)) + ((a4 + a5) + (a6 + a7));
    atomicAdd(&hc[b * 128 + m], s);
  }
}

// ---------------- conv: 128 thr = 2 waves, col-split. Tile 32 rows x 64 f-cols.
// implicit im2col, fused input-BN, double-buffered B chunks, epilogue BN-sums
__global__ __launch_bounds__(128, 2) void k_conv(
    const float* __restrict__ zin, const float* __restrict__ bnin,
    const float* __restrict__ gamv, const float* __restrict__ betv,
    const unsigned short* __restrict__ wt, const float* __restrict__ cb,
    float* __restrict__ zout, float* __restrict__ bnout, int E, int xmode) {
  extern __shared__ unsigned short smem[];
  const int SL = (E == 512) ? 520 : 264;     // slab stride: dword-stride % 32 == 4
  unsigned short* slab = smem;               // 34 x SL
  unsigned short* Bs = smem + 34 * SL;       // 2 x 64 x 72 (double-buffered)
  const int K = 3 * E, NC = K >> 6;
  const int esh = (E == 512) ? 9 : 8;
  int tid = threadIdx.x;
  int lane = tid & 63, wave = tid >> 6;
  int r0 = blockIdx.x * 32, ct = blockIdx.y;
  int i32 = lane & 31;
  int koff = (lane >> 5) << 3;

  int lrow = (r0 + i32) % 100;
  bool vks0 = (lrow >= 1), vks2 = (lrow <= 98);

  // ---- stage input slab (rows m = r0-1 .. r0+32, clamped; invalid ks masked later)
  if (xmode) {  // conv1: x is (L,B,E) fp32, E=512
    for (int s = wave; s < 34; s += 2) {
      int m = r0 - 1 + s; m = min(max(m, 0), 3199);
      int b = m / 100, l = m - b * 100;
      size_t base = (size_t)(l * 32 + b) * 512;
#pragma unroll
      for (int cc = 0; cc < 2; ++cc) {
        int ch = cc * 256 + lane * 4;
        float4 v = *(const float4*)(zin + base + ch);
        uint2 p; p.x = pk2bf(v.x, v.y); p.y = pk2bf(v.z, v.w);
        *(uint2*)(&slab[s * SL + ch]) = p;
      }
    }
  } else {      // convs 2-4: z (m,256) fp32 with BN applied on stage
    const float inv = 1.f / 3200.f;
    float sc[4], sh[4];
#pragma unroll
    for (int q = 0; q < 4; ++q) {
      int ch = lane * 4 + q;
      float mme = bnin[ch] * inv;
      float var = bnin[256 + ch] * inv - mme * mme;
      sc[q] = gamv[ch] * rsqrtf(var + 1e-5f);
      sh[q] = betv[ch] - mme * sc[q];
    }
    for (int s = wave; s < 34; s += 2) {
      int m = r0 - 1 + s; m = min(max(m, 0), 3199);
      float4 v = *(const float4*)(zin + (size_t)m * 256 + lane * 4);
      uint2 p;
      p.x = pk2bf(v.x * sc[0] + sh[0], v.y * sc[1] + sh[1]);
      p.y = pk2bf(v.z * sc[2] + sh[2], v.w * sc[3] + sh[3]);
      *(uint2*)(&slab[s * SL + lane * 4]) = p;
    }
  }

  floatx16 acc;
#pragma unroll
  for (int q = 0; q < 16; ++q) acc[q] = 0.f;

  // B staging: 64x64 bf16 chunk, 128 thr: 2 thr/row x 4 uint4
  int brow = tid >> 1, bhalf = (tid & 1) * 32;
  uint4 pre[4];
#pragma unroll
  for (int t = 0; t < 4; ++t)
    pre[t] = *(const uint4*)(wt + (size_t)(ct * 64 + brow) * K + bhalf + t * 8);

  for (int c = 0; c < NC; ++c) {
    unsigned short* Bc = Bs + (c & 1) * (64 * 72);
#pragma unroll
    for (int t = 0; t < 4; ++t)
      *(uint4*)(&Bc[brow * 72 + bhalf + t * 8]) = pre[t];
    __syncthreads();      // covers slab staging at c==0; Bc writes visible
    if (c + 1 < NC) {
#pragma unroll
      for (int t = 0; t < 4; ++t)
        pre[t] = *(const uint4*)(wt + (size_t)(ct * 64 + brow) * K + (c + 1) * 64 + bhalf + t * 8);
    }
    int ks = (c << 6) >> esh;
    int ebase = (c << 6) & (E - 1);
    bool v = (ks == 0) ? vks0 : ((ks == 2) ? vks2 : true);
    int srow = i32 + ks;
#pragma unroll
    for (int kk = 0; kk < 4; ++kk) {
      short8 a = {};
      if (v) a = *(const short8*)(&slab[srow * SL + ebase + kk * 16 + koff]);
      short8 b8 = *(const short8*)(&Bc[(wave * 32 + i32) * 72 + kk * 16 + koff]);
      acc = __builtin_amdgcn_mfma_f32_32x32x16_bf16(a, b8, acc, 0, 0, 0);
    }
  }

  // ---- epilogue: bias + lrelu, store z fp32, BN sum/sumsq atomics
  int f = ct * 64 + wave * 32 + i32;
  float bias = cb[f];
  float s1 = 0.f, s2 = 0.f;
#pragma unroll
  for (int reg = 0; reg < 16; ++reg) {
    int rowp = (reg & 3) + 8 * (reg >> 2) + 4 * (lane >> 5);
    int m = r0 + rowp;
    float v = acc[reg] + bias;
    v = fmaxf(v, NEG * v);
    zout[(size_t)m * 256 + f] = v;
    s1 += v; s2 += v * v;
  }
  s1 += __shfl_xor(s1, 32, 64);
  s2 += __shfl_xor(s2, 32, 64);
  if (lane < 32) { atomicAdd(&bnout[f], s1); atomicAdd(&bnout[256 + f], s2); }
}

// ---------------- A/C GEMM, 128 thr = 2 waves col-split, fused BN4 + coords
__global__ __launch_bounds__(128, 2) void k_ac(
    const float* __restrict__ zin, const float* __restrict__ bnin,
    const float* __restrict__ gamv, const float* __restrict__ betv,
    const unsigned short* __restrict__ wab, const float* __restrict__ hc,
    const float* __restrict__ b1v,
    unsigned short* __restrict__ Abf, unsigned short* __restrict__ Cbf) {
  __shared__ unsigned short slab[32 * 328];
  __shared__ unsigned short Bs[2 * 64 * 72];
  int tid = threadIdx.x;
  int lane = tid & 63, wave = tid >> 6;
  int r0 = blockIdx.x * 32, ct = blockIdx.y;
  int i32 = lane & 31;
  int koff = (lane >> 5) << 3;
  const float inv = 1.f / 3200.f;

  // ---- stage slab: cols 0..255 BN(z), 256/257 coords, rest zero
  {
    float sc[4], sh[4];
#pragma unroll
    for (int q = 0; q < 4; ++q) {
      int ch = lane * 4 + q;
      float mme = bnin[ch] * inv;
      float var = bnin[256 + ch] * inv - mme * mme;
      sc[q] = gamv[ch] * rsqrtf(var + 1e-5f);
      sh[q] = betv[ch] - mme * sc[q];
    }
    for (int s = wave; s < 32; s += 2) {
      int m = r0 + s;
      float4 v = *(const float4*)(zin + (size_t)m * 256 + lane * 4);
      uint2 p;
      p.x = pk2bf(v.x * sc[0] + sh[0], v.y * sc[1] + sh[1]);
      p.y = pk2bf(v.z * sc[2] + sh[2], v.w * sc[3] + sh[3]);
      *(uint2*)(&slab[s * 328 + lane * 4]) = p;
    }
    if (wave == 0) {   // coords + zero tail, cols 256..319
      int s = i32, half = (lane >> 5) * 32;
      int m = r0 + s, l = m % 100;
      float c0 = ((float)l * 0.1f - 2.0f) * 0.5f;
      float c1 = ((float)(l % 10) - 2.0f) * 0.5f;
#pragma unroll
      for (int seg = 0; seg < 4; ++seg) {
        uint4 z4; z4.x = z4.y = z4.z = z4.w = 0u;
        if (half == 0 && seg == 0) z4.x = pk2bf(c0, c1);
        *(uint4*)(&slab[s * 328 + 256 + half + seg * 8]) = z4;
      }
    }
  }

  floatx16 acc;
#pragma unroll
  for (int q = 0; q < 16; ++q) acc[q] = 0.f;

  int brow = tid >> 1, bhalf = (tid & 1) * 32;
  uint4 pre[4];
#pragma unroll
  for (int t = 0; t < 4; ++t)
    pre[t] = *(const uint4*)(wab + (size_t)(ct * 64 + brow) * 384 + bhalf + t * 8);

  for (int c = 0; c < 5; ++c) {
    unsigned short* Bc = Bs + (c & 1) * (64 * 72);
#pragma unroll
    for (int t = 0; t < 4; ++t)
      *(uint4*)(&Bc[brow * 72 + bhalf + t * 8]) = pre[t];
    __syncthreads();
    if (c + 1 < 5) {
#pragma unroll
      for (int t = 0; t < 4; ++t)
        pre[t] = *(const uint4*)(wab + (size_t)(ct * 64 + brow) * 384 + (c + 1) * 64 + bhalf + t * 8);
    }
#pragma unroll
    for (int kk = 0; kk < 4; ++kk) {
      short8 a = *(const short8*)(&slab[i32 * 328 + c * 64 + kk * 16 + koff]);
      short8 b8 = *(const short8*)(&Bc[(wave * 32 + i32) * 72 + kk * 16 + koff]);
      acc = __builtin_amdgcn_mfma_f32_32x32x16_bf16(a, b8, acc, 0, 0, 0);
    }
  }

  // ---- epilogue: ct<2 -> A half; ct>=2 -> C half (+hc+b1)
  int n = ct * 64 + wave * 32 + i32;
#pragma unroll
  for (int reg = 0; reg < 16; ++reg) {
    int rowp = (reg & 3) + 8 * (reg >> 2) + 4 * (lane >> 5);
    int m = r0 + rowp;
    float v = acc[reg];
    if (ct < 2) {
      Abf[(size_t)m * 128 + n] = (unsigned short)f2bf(v);
    } else {
      int b = m / 100;
      int nc = n - 128;
      Cbf[(size_t)m * 128 + nc] =
          (unsigned short)f2bf(v + hc[b * 128 + nc] + b1v[nc]);
    }
  }
}

// ---------------- fused relation MLP v3: of-split waves, flipped layers 1-2
// D=mfma(Wfrag, gfrag) -> D[of][pr]: contiguous-of epilogue (ds_write_b64)
// double-buffered gs; layer 3 unflipped for in-register pair-sum
__global__ __launch_bounds__(256, 2) void k_mlp(
    const unsigned short* __restrict__ Abf, const unsigned short* __restrict__ Cbf,
    const unsigned short* __restrict__ wmlp, const float* __restrict__ b2,
    const float* __restrict__ b3, const float* __restrict__ b4,
    float* __restrict__ sout) {
  __shared__ unsigned short gs0[128 * 136];
  __shared__ unsigned short gs1[128 * 136];
  int tid = threadIdx.x, lane = tid & 63, wave = tid >> 6;
  int ln31 = lane & 31;
  int half = lane >> 5;
  int koff = half << 3;
  int wb = wave * 32;

  // persistent W fragments (wmlp frag order; same [idx][k] layout serves A and B use)
  short8 wreg[3][8];
#pragma unroll
  for (int z = 0; z < 3; ++z)
#pragma unroll
    for (int kk = 0; kk < 8; ++kk)
      wreg[z][kk] = *(const short8*)(wmlp + (size_t)(((z * 4 + wave) * 8 + kk) * 512) + lane * 8);

  // bias float4 per of-quad: of = wb + q*8 + 4*half + (0..3)
  float4 bq[2][4];
#pragma unroll
  for (int q = 0; q < 4; ++q) {
    bq[0][q] = *(const float4*)(b2 + wb + q * 8 + 4 * half);
    bq[1][q] = *(const float4*)(b3 + wb + q * 8 + 4 * half);
  }
  float bv4 = b4[wb + ln31];

  for (int ti = 0; ti < 2; ++ti) {
    int t = blockIdx.x + ti * 1264;
    int b = t / 79, tt = t - b * 79;
    __syncthreads();   // prior tile's layer-3 readers done with gs0
    {  // g0 = lrelu(C_i + A_j) -> gs0[pr][k]
      int lr = wb + (lane >> 1);
      int hh = lane & 1;
      int r = tt * 128 + lr;
      if (r > 9999) r = 9999;                  // clamp; masked at final sum
      const unsigned short* Crow = Cbf + (size_t)(b * 100 + r / 100) * 128;
      const unsigned short* Arow = Abf + (size_t)(b * 100 + r % 100) * 128;
#pragma unroll
      for (int it = 0; it < 8; ++it) {
        int cc = hh * 64 + it * 8;
        uint4 c4 = *(const uint4*)(Crow + cc);
        uint4 a4 = *(const uint4*)(Arow + cc);
        unsigned cw[4] = {c4.x, c4.y, c4.z, c4.w};
        unsigned aw[4] = {a4.x, a4.y, a4.z, a4.w};
        unsigned ow[4];
#pragma unroll
        for (int q = 0; q < 4; ++q) {
          float x0 = bits2f(cw[q] << 16) + bits2f(aw[q] << 16);
          float x1 = bits2f(cw[q] & 0xFFFF0000u) + bits2f(aw[q] & 0xFFFF0000u);
          x0 = fmaxf(x0, NEG * x0);
          x1 = fmaxf(x1, NEG * x1);
          ow[q] = pk2bf(x0, x1);
        }
        uint4 o4; o4.x = ow[0]; o4.y = ow[1]; o4.z = ow[2]; o4.w = ow[3];
        *(uint4*)(&gs0[lr * 136 + cc]) = o4;
      }
    }
    __syncthreads();

    // ---- layers 0,1 flipped: D[of][pr] = sum_k W[k][of] g[pr][k]
#pragma unroll
    for (int z = 0; z < 2; ++z) {
      const unsigned short* src = z ? gs1 : gs0;
      unsigned short* dst = z ? gs0 : gs1;
#pragma unroll
      for (int rg = 0; rg < 4; ++rg) {
        floatx16 acc;
#pragma unroll
        for (int q = 0; q < 16; ++q) acc[q] = 0.f;
#pragma unroll
        for (int kk = 0; kk < 8; ++kk) {
          short8 g8 = *(const short8*)(&src[(rg * 32 + ln31) * 136 + kk * 16 + koff]);
          acc = __builtin_amdgcn_mfma_f32_32x32x16_bf16(wreg[z][kk], g8, acc, 0, 0, 0);
        }
        int pr = rg * 32 + ln31;
#pragma unroll
        for (int q = 0; q < 4; ++q) {
          float4 bb = bq[z][q];
          float v0 = acc[q * 4 + 0] + bb.x; v0 = fmaxf(v0, NEG * v0);
          float v1 = acc[q * 4 + 1] + bb.y; v1 = fmaxf(v1, NEG * v1);
          float v2 = acc[q * 4 + 2] + bb.z; v2 = fmaxf(v2, NEG * v2);
          float v3 = acc[q * 4 + 3] + bb.w; v3 = fmaxf(v3, NEG * v3);
          uint2 p; p.x = pk2bf(v0, v1); p.y = pk2bf(v2, v3);
          *(uint2*)(&dst[pr * 136 + wb + q * 8 + 4 * half]) = p;
        }
      }
      __syncthreads();
    }

    // ---- layer 2 unflipped: D[pr][of], reduce over pr in-register
    float colsum = 0.f;
#pragma unroll
    for (int rg = 0; rg < 4; ++rg) {
      floatx16 acc;
#pragma unroll
      for (int q = 0; q < 16; ++q) acc[q] = 0.f;
#pragma unroll
      for (int kk = 0; kk < 8; ++kk) {
        short8 a8 = *(const short8*)(&gs0[(rg * 32 + ln31) * 136 + kk * 16 + koff]);
        acc = __builtin_amdgcn_mfma_f32_32x32x16_bf16(a8, wreg[2][kk], acc, 0, 0, 0);
      }
#pragma unroll
      for (int reg = 0; reg < 16; ++reg) {
        int rowp = (reg & 3) + 8 * (reg >> 2) + 4 * half;
        int p = tt * 128 + rg * 32 + rowp;
        float v = acc[reg] + bv4;
        v = fmaxf(v, NEG * v);
        colsum += (p < 10000) ? v : 0.f;
      }
    }
    colsum += __shfl_xor(colsum, 32, 64);
    if (lane < 32) atomicAdd(&sout[b * 128 + wb + lane], colsum);
  }
}

// ---------------- final: out = lrelu(lrelu(s@F1+fb1)@F2+fb2), one block per b
__global__ void k_final(const float* __restrict__ s, const float* __restrict__ F1,
                        const float* __restrict__ fb1, const float* __restrict__ F2,
                        const float* __restrict__ fb2, float* __restrict__ out) {
  __shared__ float sl[128], t1[128];
  int b = blockIdx.x, t = threadIdx.x;
  if (t < 128) sl[t] = s[b * 128 + t];
  __syncthreads();
  if (t < 128) {
    float a = fb1[t];
    for (int k = 0; k < 128; ++k) a += sl[k] * F1[k * 128 + t];
    t1[t] = fmaxf(a, NEG * a);
  }
  __syncthreads();
  for (int o = t; o < 512; o += 256) {
    float a = fb2[o];
    for (int k = 0; k < 128; ++k) a += t1[k] * F2[k * 512 + o];
    out[b * 512 + o] = fmaxf(a, NEG * a);
  }
}

extern "C" void kernel_launch(void* const* d_in, const int* in_sizes, int n_in,
                              void* d_out, int out_size, void* d_ws, size_t ws_size,
                              hipStream_t stream) {
  const float* x   = (const float*)d_in[0];
  const float* h   = (const float*)d_in[1];
  const float* cw1 = (const float*)d_in[2];
  const float* cb1 = (const float*)d_in[3];
  const float* g1  = (const float*)d_in[4];
  const float* be1 = (const float*)d_in[5];
  const float* cw2 = (const float*)d_in[6];
  const float* cb2 = (const float*)d_in[7];
  const float* g2  = (const float*)d_in[8];
  const float* be2 = (const float*)d_in[9];
  const float* cw3 = (const float*)d_in[10];
  const float* cb3 = (const float*)d_in[11];
  const float* g3  = (const float*)d_in[12];
  const float* be3 = (const float*)d_in[13];
  const float* cw4 = (const float*)d_in[14];
  const float* cb4 = (const float*)d_in[15];
  const float* g4  = (const float*)d_in[16];
  const float* be4 = (const float*)d_in[17];
  const float* W1  = (const float*)d_in[18];
  const float* b1  = (const float*)d_in[19];
  const float* W2  = (const float*)d_in[20];
  const float* b2  = (const float*)d_in[21];
  const float* W3  = (const float*)d_in[22];
  const float* b3  = (const float*)d_in[23];
  const float* W4  = (const float*)d_in[24];
  const float* b4  = (const float*)d_in[25];
  const float* F1  = (const float*)d_in[26];
  const float* fb1 = (const float*)d_in[27];
  const float* F2  = (const float*)d_in[28];
  const float* fb2 = (const float*)d_in[29];

  char* ws = (char*)d_ws;
  float* bn0  = (float*)(ws + 0);
  float* bn1  = (float*)(ws + 2048);
  float* bn2  = (float*)(ws + 4096);
  float* bn3  = (float*)(ws + 6144);
  float* sbuf = (float*)(ws + 8192);                        // 32x128 fp32
  float* hc   = (float*)(ws + 24576);                       // 32x128 fp32 (zeroed)
  float* za   = (float*)(ws + 40960);                       // 3200x256 fp32
  float* zb   = (float*)(ws + 3317760);                     // 3200x256 fp32
  unsigned short* wt1  = (unsigned short*)(ws + 6594560);   // 256x1536 bf16
  unsigned short* wt2  = (unsigned short*)(ws + 7380992);   // 256x768
  unsigned short* wt3  = (unsigned short*)(ws + 7774208);
  unsigned short* wt4  = (unsigned short*)(ws + 8167424);
  unsigned short* wab  = (unsigned short*)(ws + 8560640);   // 256x384
  unsigned short* wmlp = (unsigned short*)(ws + 8757248);   // 3x16384 frag-order
  unsigned short* Abf  = (unsigned short*)(ws + 8855552);   // 3200x128 bf16
  unsigned short* Cbf  = (unsigned short*)(ws + 9674752);   // 3200x128 bf16; end 10493952

  hipMemsetAsync(d_ws, 0, 40960, stream);     // bn sums + s accumulator + hc

  k_prep<<<1624, 256, 0, stream>>>(cw1, cw2, cw3, cw4, wt1, wt2, wt3, wt4,
                                   W1, wab, W2, W3, W4, wmlp, h, hc);

  const int lds1 = (34 * 520 + 2 * 64 * 72) * 2;   // 53792 B
  const int lds2 = (34 * 264 + 2 * 64 * 72) * 2;   // 36384 B
  k_conv<<<dim3(100, 4), 128, lds1, stream>>>(x,  nullptr, nullptr, nullptr, wt1, cb1, za, bn0, 512, 1);
  k_conv<<<dim3(100, 4), 128, lds2, stream>>>(za, bn0, g1, be1, wt2, cb2, zb, bn1, 256, 0);
  k_conv<<<dim3(100, 4), 128, lds2, stream>>>(zb, bn1, g2, be2, wt3, cb3, za, bn2, 256, 0);
  k_conv<<<dim3(100, 4), 128, lds2, stream>>>(za, bn2, g3, be3, wt4, cb4, zb, bn3, 256, 0);

  k_ac<<<dim3(100, 4), 128, 0, stream>>>(zb, bn3, g4, be4, wab, hc, b1, Abf, Cbf);

  k_mlp<<<1264, 256, 0, stream>>>(Abf, Cbf, wmlp, b2, b3, b4, sbuf);
  k_final<<<32, 256, 0, stream>>>(sbuf, F1, fb1, F2, fb2, (float*)d_out);
}